// Round 1
// baseline (1914.958 us; speedup 1.0000x reference)
//
#include <hip/hip_runtime.h>
#include <hip/hip_bf16.h>
#include <stdint.h>
#include <math.h>

// ---------------- problem constants ----------------
#define NB    8192            // batch
#define INDIM 2048
#define EMB   256
#define H1N   1024
#define H2N   512
#define KCB   1024            // codebook size
#define NLAYER 3
// PRNG mode: 0 = jax threefry_partitionable (default since jax 0.4.30)
//            1 = legacy/original threefry scheme
#define PRNG_MODE 0

// ---------------- threefry2x32 (20 rounds) ----------------
__host__ __device__ inline void tf2x32(uint32_t k0, uint32_t k1, uint32_t x0, uint32_t x1,
                                       uint32_t& o0, uint32_t& o1)
{
  const uint32_t ks2 = 0x1BD11BDAu ^ k0 ^ k1;
  uint32_t a = x0 + k0, b = x1 + k1;
#define TF_RND(r) { a += b; b = (b << (r)) | (b >> (32 - (r))); b ^= a; }
  TF_RND(13) TF_RND(15) TF_RND(26) TF_RND(6)
  a += k1; b += ks2 + 1u;
  TF_RND(17) TF_RND(29) TF_RND(16) TF_RND(24)
  a += ks2; b += k0 + 2u;
  TF_RND(13) TF_RND(15) TF_RND(26) TF_RND(6)
  a += k0; b += k1 + 3u;
  TF_RND(17) TF_RND(29) TF_RND(16) TF_RND(24)
  a += k1; b += ks2 + 4u;
  TF_RND(13) TF_RND(15) TF_RND(26) TF_RND(6)
  a += ks2; b += k0 + 5u;
#undef TF_RND
  o0 = a; o1 = b;
}

// ---------------- helpers ----------------
__device__ inline float blk_reduce_sum(float v, float* sbuf)
{
  const int t = threadIdx.x;
  sbuf[t] = v; __syncthreads();
  for (int s = 128; s > 0; s >>= 1) {
    if (t < s) sbuf[t] += sbuf[t + s];
    __syncthreads();
  }
  float r = sbuf[0];
  __syncthreads();
  return r;
}

// ---------------- fp32 tiled GEMM: C[M,N] = A[M,K] @ (BT ? B[N,K]^T : B[K,N]) ---------
template<bool BT>
__global__ __launch_bounds__(256) void sgemm128(const float* __restrict__ A,
                                                const float* __restrict__ B,
                                                float* __restrict__ C,
                                                int M, int N, int K)
{
  __shared__ float As[8][128];
  __shared__ float Bs[8][128];
  const int tid = threadIdx.x;
  const int tx = tid & 15, ty = tid >> 4;
  const size_t brow = (size_t)blockIdx.y * 128;
  const size_t bcol = (size_t)blockIdx.x * 128;

  float acc[2][2][4][4];
#pragma unroll
  for (int a = 0; a < 2; a++)
#pragma unroll
    for (int b = 0; b < 2; b++)
#pragma unroll
      for (int i = 0; i < 4; i++)
#pragma unroll
        for (int j = 0; j < 4; j++) acc[a][b][i][j] = 0.f;

  const int am = tid >> 1;            // 0..127
  const int ak = (tid & 1) * 4;       // 0 or 4
  const int bk = tid >> 5;            // 0..7   (NN loader)
  const int bn = (tid & 31) * 4;      // 0..124 (NN loader)

  for (int k0 = 0; k0 < K; k0 += 8) {
    float4 av = *reinterpret_cast<const float4*>(&A[(brow + am) * K + k0 + ak]);
    As[ak + 0][am] = av.x; As[ak + 1][am] = av.y;
    As[ak + 2][am] = av.z; As[ak + 3][am] = av.w;
    if (BT) {
      float4 bv = *reinterpret_cast<const float4*>(&B[(bcol + am) * K + k0 + ak]);
      Bs[ak + 0][am] = bv.x; Bs[ak + 1][am] = bv.y;
      Bs[ak + 2][am] = bv.z; Bs[ak + 3][am] = bv.w;
    } else {
      float4 bv = *reinterpret_cast<const float4*>(&B[(size_t)(k0 + bk) * N + bcol + bn]);
      *reinterpret_cast<float4*>(&Bs[bk][bn]) = bv;
    }
    __syncthreads();
#pragma unroll
    for (int kk = 0; kk < 8; ++kk) {
      float a0[4], a1[4], b0[4], b1[4];
#pragma unroll
      for (int i = 0; i < 4; i++) {
        a0[i] = As[kk][ty * 4 + i];
        a1[i] = As[kk][64 + ty * 4 + i];
        b0[i] = Bs[kk][tx * 4 + i];
        b1[i] = Bs[kk][64 + tx * 4 + i];
      }
#pragma unroll
      for (int i = 0; i < 4; i++)
#pragma unroll
        for (int j = 0; j < 4; j++) {
          acc[0][0][i][j] += a0[i] * b0[j];
          acc[0][1][i][j] += a0[i] * b1[j];
          acc[1][0][i][j] += a1[i] * b0[j];
          acc[1][1][i][j] += a1[i] * b1[j];
        }
    }
    __syncthreads();
  }
#pragma unroll
  for (int a = 0; a < 2; a++) {
    const size_t crow = brow + a * 64 + ty * 4;
#pragma unroll
    for (int b = 0; b < 2; b++) {
      const size_t ccol = bcol + b * 64 + tx * 4;
#pragma unroll
      for (int i = 0; i < 4; i++) {
        float4 v = make_float4(acc[a][b][i][0], acc[a][b][i][1],
                               acc[a][b][i][2], acc[a][b][i][3]);
        *reinterpret_cast<float4*>(&C[(crow + i) * N + ccol]) = v;
      }
    }
  }
}

// ---------------- fused SiLU + LayerNorm (in-place, one block per row) ----------------
template<int NCOL>
__global__ __launch_bounds__(256) void silu_ln(float* __restrict__ buf,
                                               const float* __restrict__ g,
                                               const float* __restrict__ bta)
{
  constexpr int PT = NCOL / 256;
  __shared__ float sb[256];
  const int b = blockIdx.x, t = threadIdx.x;
  float* row = buf + (size_t)b * NCOL;
  float v[PT];
  float s = 0.f;
#pragma unroll
  for (int i = 0; i < PT; i++) {
    float x = row[t + 256 * i];
    float sv = x / (1.f + expf(-x));
    v[i] = sv; s += sv;
  }
  s = blk_reduce_sum(s, sb);
  const float mu = s / (float)NCOL;
  float q = 0.f;
#pragma unroll
  for (int i = 0; i < PT; i++) { float d = v[i] - mu; q += d * d; }
  q = blk_reduce_sum(q, sb);
  const float inv = 1.f / sqrtf(q / (float)NCOL + 1e-5f);
#pragma unroll
  for (int i = 0; i < PT; i++) {
    const int c = t + 256 * i;
    row[c] = (v[i] - mu) * inv * g[c] + bta[c];
  }
}

// ---------------- codebook squared norms: cn2[l*1024+j] ----------------
__global__ __launch_bounds__(64) void colnorm2(const float* __restrict__ cb,
                                               float* __restrict__ cn2)
{
  const int r = blockIdx.x, t = threadIdx.x;   // 3072 rows, 64 threads
  const float* row = cb + (size_t)r * EMB;
  float s = 0.f;
#pragma unroll
  for (int i = 0; i < 4; i++) { float v = row[t + 64 * i]; s += v * v; }
  for (int off = 32; off > 0; off >>= 1) s += __shfl_down(s, off);
  if (t == 0) cn2[r] = s;
}

// ---------------- gumbel-max sampler (exact jax.random.categorical) ----------------
__global__ __launch_bounds__(256) void sampler(const float* __restrict__ S,
                                               const float* __restrict__ cn2,
                                               int* __restrict__ ids,
                                               uint32_t k0, uint32_t k1, int layer)
{
  __shared__ float sv[256];
  __shared__ int   si[256];
  const int b = blockIdx.x, t = threadIdx.x;
  const float* Srow = S + (size_t)b * KCB;
  float best = -INFINITY; int bestj = 0x7fffffff;
#pragma unroll
  for (int jj = 0; jj < 4; ++jj) {
    const int j = t + jj * 256;
    const uint32_t idx = (uint32_t)(b * KCB + j);
    uint32_t o0, o1, bits;
#if PRNG_MODE == 0
    tf2x32(k0, k1, 0u, idx, o0, o1);
    bits = o0 ^ o1;
#else
    const uint32_t half = (uint32_t)(NB * KCB / 2);
    if (idx < half) { tf2x32(k0, k1, idx, idx + half, o0, o1); bits = o0; }
    else            { tf2x32(k0, k1, idx - half, idx, o0, o1); bits = o1; }
#endif
    float f = __uint_as_float((bits >> 9) | 0x3f800000u) - 1.0f;
    float u = fmaxf(f, 1.17549435e-38f);
    float gmb = -logf(-logf(u));
    float logit = (2.0f * Srow[j] - cn2[j]) / 1.25f;   // per-row const omitted (argmax-invariant)
    float val = gmb + logit;
    if (val > best || (val == best && j < bestj)) { best = val; bestj = j; }
  }
  sv[t] = best; si[t] = bestj; __syncthreads();
  for (int s = 128; s > 0; s >>= 1) {
    if (t < s) {
      float v2 = sv[t + s]; int j2 = si[t + s];
      if (v2 > sv[t] || (v2 == sv[t] && j2 < si[t])) { sv[t] = v2; si[t] = j2; }
    }
    __syncthreads();
  }
  if (t == 0) ids[b * NLAYER + layer] = si[0];
}

// ---------------- rotation-trick quantize update (one block per row) ----------------
__global__ __launch_bounds__(256) void quant_update(float* __restrict__ res,
                                                    float* __restrict__ esum,
                                                    const float* __restrict__ cb,
                                                    const int* __restrict__ ids,
                                                    float* __restrict__ qrow,
                                                    float* __restrict__ outEn,
                                                    int layer)
{
  __shared__ float sb[256];
  const int b = blockIdx.x, t = threadIdx.x;
  const float r = res[(size_t)b * EMB + t];
  const int id = ids[b * NLAYER + layer];
  const float e_ = cb[(size_t)id * EMB + t];

  const float rn2 = blk_reduce_sum(r * r, sb);
  const float en2 = blk_reduce_sum(e_ * e_, sb);
  const float rn = sqrtf(rn2), en = sqrtf(en2);
  const float u = r / (rn + 1e-8f);
  const float q = e_ / (en + 1e-8f);
  const float s = u + q;
  const float sn2 = blk_reduce_sum(s * s, sb);
  const float w = s / fmaxf(sqrtf(sn2), 1e-6f);
  const float rw = blk_reduce_sum(r * w, sb);
  const float ru = blk_reduce_sum(r * u, sb);
  const float e = r - 2.f * rw * w + 2.f * ru * q;
  const float eo2 = blk_reduce_sum(e * e, sb);
  const float dq = r - e_;
  const float ql = blk_reduce_sum(dq * dq, sb);

  if (t == 0) {
    outEn[b * NLAYER + layer] = sqrtf(eo2);
    if (layer == 0) qrow[b] = 1.25f * ql; else qrow[b] += 1.25f * ql;
  }
  res[(size_t)b * EMB + t] = r - e;
  if (layer == 0) esum[(size_t)b * EMB + t] = e;
  else            esum[(size_t)b * EMB + t] += e;
}

// ---------------- final l2norm + per-row recon ----------------
__global__ __launch_bounds__(256) void l2norm_recon(const float* __restrict__ y,
                                                    const float* __restrict__ x,
                                                    float* __restrict__ recon)
{
  __shared__ float sb[256];
  const int b = blockIdx.x, t = threadIdx.x;
  const float* yr = y + (size_t)b * INDIM;
  const float* xr = x + (size_t)b * INDIM;
  float vy[8];
  float ss = 0.f;
#pragma unroll
  for (int i = 0; i < 8; i++) { vy[i] = yr[t + 256 * i]; ss += vy[i] * vy[i]; }
  ss = blk_reduce_sum(ss, sb);
  const float inv = 1.f / fmaxf(sqrtf(ss), 1e-12f);
  float acc = 0.f;
#pragma unroll
  for (int i = 0; i < 8; i++) {
    float d = vy[i] * inv - xr[t + 256 * i];
    acc += d * d;
  }
  acc = blk_reduce_sum(acc, sb);
  if (t == 0) recon[b] = acc;
}

// ---------------- p_unique ----------------
__global__ __launch_bounds__(256) void pack_ids(const int* __restrict__ ids,
                                                uint32_t* __restrict__ packed)
{
  const int i = blockIdx.x * 256 + threadIdx.x;
  if (i < NB)
    packed[i] = (uint32_t)ids[i * 3] | ((uint32_t)ids[i * 3 + 1] << 10)
              | ((uint32_t)ids[i * 3 + 2] << 20);
}

__global__ __launch_bounds__(256) void unique_count(const uint32_t* __restrict__ packed,
                                                    int* __restrict__ part)
{
  __shared__ uint32_t sp[NB];
  __shared__ int sc[256];
  const int t = threadIdx.x;
  for (int i = t; i < NB; i += 256) sp[i] = packed[i];
  __syncthreads();
  const int row = blockIdx.x * 256 + t;
  int cnt = 0;
  {
    const uint32_t v = sp[row];
    bool dup = false;
    for (int j = row + 1; j < NB; j++) dup |= (sp[j] == v);
    cnt = dup ? 0 : 1;
  }
  sc[t] = cnt; __syncthreads();
  for (int s = 128; s > 0; s >>= 1) { if (t < s) sc[t] += sc[t + s]; __syncthreads(); }
  if (t == 0) part[blockIdx.x] = sc[0];
}

// ---------------- finalize scalars ----------------
__global__ __launch_bounds__(256) void finalize(const float* __restrict__ recon,
                                                const float* __restrict__ qrow,
                                                const int* __restrict__ upart,
                                                float* __restrict__ out)
{
  __shared__ double sd[256];
  __shared__ int si[256];
  const int t = threadIdx.x;
  double aR = 0.0, aQ = 0.0;
  for (int i = t; i < NB; i += 256) { aR += (double)recon[i]; aQ += (double)qrow[i]; }
  sd[t] = aR; __syncthreads();
  for (int s = 128; s > 0; s >>= 1) { if (t < s) sd[t] += sd[t + s]; __syncthreads(); }
  const double sumR = sd[0]; __syncthreads();
  sd[t] = aQ; __syncthreads();
  for (int s = 128; s > 0; s >>= 1) { if (t < s) sd[t] += sd[t + s]; __syncthreads(); }
  const double sumQ = sd[0]; __syncthreads();
  si[t] = (t < 32) ? upart[t] : 0; __syncthreads();
  for (int s = 128; s > 0; s >>= 1) { if (t < s) si[t] += si[t + s]; __syncthreads(); }
  if (t == 0) {
    const float rm = (float)(sumR / (double)NB);
    const float ql = (float)sumQ;
    out[0] = rm + ql;                       // loss
    out[1] = rm;                            // recon.mean()
    out[2] = ql;                            // quant_loss
    out[3 + NB * NLAYER] = (float)si[0] / (float)NB;  // p_unique
  }
}

// ---------------- host launch ----------------
extern "C" void kernel_launch(void* const* d_in, const int* in_sizes, int n_in,
                              void* d_out, int out_size, void* d_ws, size_t ws_size,
                              hipStream_t stream)
{
  const float* x      = (const float*)d_in[0];
  const float* enc_w1 = (const float*)d_in[1];
  const float* enc_g1 = (const float*)d_in[2];
  const float* enc_b1 = (const float*)d_in[3];
  const float* enc_w2 = (const float*)d_in[4];
  const float* enc_g2 = (const float*)d_in[5];
  const float* enc_b2 = (const float*)d_in[6];
  const float* enc_w3 = (const float*)d_in[7];
  const float* dec_w1 = (const float*)d_in[8];
  const float* dec_g1 = (const float*)d_in[9];
  const float* dec_b1 = (const float*)d_in[10];
  const float* dec_w2 = (const float*)d_in[11];
  const float* dec_g2 = (const float*)d_in[12];
  const float* dec_b2 = (const float*)d_in[13];
  const float* dec_w3 = (const float*)d_in[14];
  const float* codebooks = (const float*)d_in[15];
  float* out = (float*)d_out;

  float* ws = (float*)d_ws;
  // float-offset layout
  const size_t S_OFF    = 0;                         // 8192*1024       (later: d2)
  const size_t H1_OFF   = 8388608;                   // 8192*1024
  const size_t H2_OFF   = 16777216;                  // 8192*512        (later: d1)
  const size_t RES_OFF  = 20971520;                  // 8192*256
  const size_t ESUM_OFF = 23068672;                  // 8192*256
  const size_t Y_OFF    = 16777216;                  // 8192*2048 (reuses h2/res/esum region)
  const size_t SM_OFF   = 33554432;
  float* S    = ws + S_OFF;
  float* h1   = ws + H1_OFF;
  float* h2   = ws + H2_OFF;
  float* res  = ws + RES_OFF;
  float* esum = ws + ESUM_OFF;
  float* y    = ws + Y_OFF;
  float* d1   = h2;     // [8192,512]
  float* d2   = S;      // [8192,1024]
  float* cn2   = ws + SM_OFF;            // 3072
  float* recon = ws + SM_OFF + 4096;     // 8192
  float* qrow  = ws + SM_OFF + 12288;    // 8192
  int*   ids   = (int*)(ws + SM_OFF + 20480);      // 8192*3
  uint32_t* packed = (uint32_t*)(ws + SM_OFF + 45056); // 8192
  int*   upart = (int*)(ws + SM_OFF + 53248);      // 32

  // PRNG keys: jax.random.split(jax.random.key(42), 3)
  uint32_t key0[NLAYER], key1[NLAYER];
#if PRNG_MODE == 0
  for (int l = 0; l < NLAYER; l++) tf2x32(0u, 42u, 0u, (uint32_t)l, key0[l], key1[l]);
#else
  {
    uint32_t a0,b0,a1,b1,a2,b2;
    tf2x32(0u,42u, 0u,3u, a0,b0);
    tf2x32(0u,42u, 1u,4u, a1,b1);
    tf2x32(0u,42u, 2u,5u, a2,b2);
    key0[0]=a0; key1[0]=a1;
    key0[1]=a2; key1[1]=b0;
    key0[2]=b1; key1[2]=b2;
  }
#endif

  dim3 blk(256);
  // ---- encoder ----
  sgemm128<false><<<dim3(H1N/128, NB/128), blk, 0, stream>>>(x, enc_w1, h1, NB, H1N, INDIM);
  silu_ln<H1N><<<NB, blk, 0, stream>>>(h1, enc_g1, enc_b1);
  sgemm128<false><<<dim3(H2N/128, NB/128), blk, 0, stream>>>(h1, enc_w2, h2, NB, H2N, H1N);
  silu_ln<H2N><<<NB, blk, 0, stream>>>(h2, enc_g2, enc_b2);
  sgemm128<false><<<dim3(EMB/128, NB/128), blk, 0, stream>>>(h2, enc_w3, res, NB, EMB, H2N);

  // ---- quantization ----
  colnorm2<<<NLAYER * KCB, dim3(64), 0, stream>>>(codebooks, cn2);
  for (int l = 0; l < NLAYER; l++) {
    const float* cb = codebooks + (size_t)l * KCB * EMB;
    sgemm128<true><<<dim3(KCB/128, NB/128), blk, 0, stream>>>(res, cb, S, NB, KCB, EMB);
    sampler<<<NB, blk, 0, stream>>>(S, cn2 + l * KCB, ids, key0[l], key1[l], l);
    quant_update<<<NB, blk, 0, stream>>>(res, esum, cb, ids, qrow, out + 3, l);
  }

  // ---- decoder ----
  sgemm128<false><<<dim3(H2N/128, NB/128), blk, 0, stream>>>(esum, dec_w1, d1, NB, H2N, EMB);
  silu_ln<H2N><<<NB, blk, 0, stream>>>(d1, dec_g1, dec_b1);
  sgemm128<false><<<dim3(H1N/128, NB/128), blk, 0, stream>>>(d1, dec_w2, d2, NB, H1N, H2N);
  silu_ln<H1N><<<NB, blk, 0, stream>>>(d2, dec_g2, dec_b2);
  sgemm128<false><<<dim3(INDIM/128, NB/128), blk, 0, stream>>>(d2, dec_w3, y, NB, INDIM, H1N);
  l2norm_recon<<<NB, blk, 0, stream>>>(y, x, recon);

  // ---- p_unique + scalars ----
  pack_ids<<<NB/256, blk, 0, stream>>>(ids, packed);
  unique_count<<<NB/256, blk, 0, stream>>>(packed, upart);
  finalize<<<1, blk, 0, stream>>>(recon, qrow, upart, out);
}

// Round 2
// 1079.551 us; speedup vs baseline: 1.7738x; 1.7738x over previous
//
#include <hip/hip_runtime.h>
#include <hip/hip_bf16.h>
#include <stdint.h>
#include <math.h>

// ---------------- problem constants ----------------
#define NB    8192
#define INDIM 2048
#define EMB   256
#define H1N   1024
#define H2N   512
#define KCB   1024
#define NLAYER 3

typedef short  s16x8 __attribute__((ext_vector_type(8)));
typedef float  f32x4 __attribute__((ext_vector_type(4)));

__device__ __host__ inline float bf2f_h(uint32_t u) { union { uint32_t i; float f; } c; c.i = u << 16; return c.f; }
__device__ inline float bf2f(ushort u) { return __uint_as_float(((uint32_t)u) << 16); }
__device__ inline ushort f2bf(float f) {
  uint32_t u = __float_as_uint(f);
  return (ushort)((u + 0x7fffu + ((u >> 16) & 1u)) >> 16);
}

#define GLD16(g, p) __builtin_amdgcn_global_load_lds( \
    (const __attribute__((address_space(1))) void*)(g), \
    (__attribute__((address_space(3))) void*)(p), 16, 0, 0)

// ---------------- threefry2x32 (20 rounds) ----------------
__host__ __device__ inline void tf2x32(uint32_t k0, uint32_t k1, uint32_t x0, uint32_t x1,
                                       uint32_t& o0, uint32_t& o1)
{
  const uint32_t ks2 = 0x1BD11BDAu ^ k0 ^ k1;
  uint32_t a = x0 + k0, b = x1 + k1;
#define TF_RND(r) { a += b; b = (b << (r)) | (b >> (32 - (r))); b ^= a; }
  TF_RND(13) TF_RND(15) TF_RND(26) TF_RND(6)
  a += k1; b += ks2 + 1u;
  TF_RND(17) TF_RND(29) TF_RND(16) TF_RND(24)
  a += ks2; b += k0 + 2u;
  TF_RND(13) TF_RND(15) TF_RND(26) TF_RND(6)
  a += k0; b += k1 + 3u;
  TF_RND(17) TF_RND(29) TF_RND(16) TF_RND(24)
  a += k1; b += ks2 + 4u;
  TF_RND(13) TF_RND(15) TF_RND(26) TF_RND(6)
  a += ks2; b += k0 + 5u;
#undef TF_RND
  o0 = a; o1 = b;
}

__device__ inline float blk_reduce_sum(float v, float* sbuf)
{
  const int t = threadIdx.x;
  sbuf[t] = v; __syncthreads();
  for (int s = 128; s > 0; s >>= 1) {
    if (t < s) sbuf[t] += sbuf[t + s];
    __syncthreads();
  }
  float r = sbuf[0];
  __syncthreads();
  return r;
}

// =================== MFMA GEMM ===================
// C[M,N] = A[M,K] * B[N,K]^T   (B stored row-major [N,K], "B^T layout")
// NS = number of bf16 splits (1 or 3); AF32: A is fp32, split in-register.
// 3-split: 6 products (i+j<=2) => ~2^-27 relative input error (fp32-class).
template<int NS, int AF32, int OUTBF>
__global__ __launch_bounds__(256) void mgemm(
    const void* __restrict__ Ap0, const ushort* __restrict__ A1p, const ushort* __restrict__ A2p,
    const ushort* __restrict__ B0p, const ushort* __restrict__ B1p, const ushort* __restrict__ B2p,
    void* __restrict__ Cp, int M, int N, int K)
{
  constexpr int ABYTES = AF32 ? 16384 : NS * 8192;
  constexpr int SMB = ABYTES + NS * 8192;
  __shared__ __align__(16) char sm[SMB];
  char* smA = sm;
  char* smB = sm + ABYTES;

  const int tid = threadIdx.x;
  const int w = tid >> 6, l = tid & 63;
  const int wm = w >> 1, wn = w & 1;
  const size_t brow = (size_t)blockIdx.y * 128;
  const size_t bcol = (size_t)blockIdx.x * 128;

  // staging (pre-swizzled global source; linear LDS dest)
  const int brow16 = w * 16 + (l >> 2);
  const int bcol16 = ((l & 3) ^ ((l >> 3) & 3)) * 8;
  const int brow32 = w * 8 + (l >> 3);
  const int bcol32 = ((l & 7) ^ (l >> 3)) * 4;

  const float* gAf = nullptr;
  const ushort *gA0 = nullptr, *gA1 = nullptr, *gA2 = nullptr;
  if constexpr (AF32) {
    gAf = (const float*)Ap0 + (brow + brow32) * (size_t)K + bcol32;
  } else {
    gA0 = (const ushort*)Ap0 + (brow + brow16) * (size_t)K + bcol16;
    if constexpr (NS >= 2) gA1 = A1p + (brow + brow16) * (size_t)K + bcol16;
    if constexpr (NS >= 3) gA2 = A2p + (brow + brow16) * (size_t)K + bcol16;
  }
  const ushort* gB0 = B0p + (bcol + brow16) * (size_t)K + bcol16;
  const ushort* gB1 = nullptr; const ushort* gB2 = nullptr;
  if constexpr (NS >= 2) gB1 = B1p + (bcol + brow16) * (size_t)K + bcol16;
  if constexpr (NS >= 3) gB2 = B2p + (bcol + brow16) * (size_t)K + bcol16;

  f32x4 acc[4][4];
#pragma unroll
  for (int i = 0; i < 4; i++)
#pragma unroll
    for (int j = 0; j < 4; j++) acc[i][j] = (f32x4){0.f, 0.f, 0.f, 0.f};

  const int srow = l & 15;
  const int ksel = l >> 4;
  const int sel2 = (srow >> 1) & 3;
  const int sel3 = srow & 7;
  const int fslot16 = (ksel ^ sel2) * 16;
  const int fs32a = ((ksel * 2) ^ sel3) * 16;
  const int fs32b = ((ksel * 2 + 1) ^ sel3) * 16;

  for (int k0 = 0; k0 < K; k0 += 32) {
    // ---- stage ----
    if constexpr (AF32) {
#pragma unroll
      for (int i = 0; i < 4; i++)
        GLD16(gAf + (size_t)(i * 32) * K + k0, smA + i * 4096 + w * 1024);
    } else {
#pragma unroll
      for (int i = 0; i < 2; i++) {
        GLD16(gA0 + (size_t)(i * 64) * K + k0, smA + i * 4096 + w * 1024);
        if constexpr (NS >= 2) GLD16(gA1 + (size_t)(i * 64) * K + k0, smA + 8192 + i * 4096 + w * 1024);
        if constexpr (NS >= 3) GLD16(gA2 + (size_t)(i * 64) * K + k0, smA + 16384 + i * 4096 + w * 1024);
      }
    }
#pragma unroll
    for (int i = 0; i < 2; i++) {
      GLD16(gB0 + (size_t)(i * 64) * K + k0, smB + i * 4096 + w * 1024);
      if constexpr (NS >= 2) GLD16(gB1 + (size_t)(i * 64) * K + k0, smB + 8192 + i * 4096 + w * 1024);
      if constexpr (NS >= 3) GLD16(gB2 + (size_t)(i * 64) * K + k0, smB + 16384 + i * 4096 + w * 1024);
    }
    __syncthreads();

    // ---- fragments ----
    s16x8 a0[4], a1[4], a2[4];
    if constexpr (AF32) {
#pragma unroll
      for (int i = 0; i < 4; i++) {
        const char* rp = smA + (wm * 64 + i * 16 + srow) * 128;
        float4 f0 = *(const float4*)(rp + fs32a);
        float4 f1 = *(const float4*)(rp + fs32b);
        float ff[8] = {f0.x, f0.y, f0.z, f0.w, f1.x, f1.y, f1.z, f1.w};
#pragma unroll
        for (int e = 0; e < 8; e++) {
          float x = ff[e];
          ushort h = f2bf(x);
          float r1 = x - bf2f(h);
          ushort mm = f2bf(r1);
          a0[i][e] = (short)h;
          a1[i][e] = (short)mm;
          a2[i][e] = (short)f2bf(r1 - bf2f(mm));
        }
      }
    } else {
#pragma unroll
      for (int i = 0; i < 4; i++) {
        const int rb = (wm * 64 + i * 16 + srow) * 64 + fslot16;
        a0[i] = *(const s16x8*)(smA + rb);
        if constexpr (NS >= 2) a1[i] = *(const s16x8*)(smA + 8192 + rb);
        if constexpr (NS >= 3) a2[i] = *(const s16x8*)(smA + 16384 + rb);
      }
    }

#pragma unroll
    for (int j = 0; j < 4; j++) {
      const int rb = (wn * 64 + j * 16 + srow) * 64 + fslot16;
      s16x8 b0 = *(const s16x8*)(smB + rb);
      s16x8 b1{}, b2{};
      if constexpr (NS >= 2) b1 = *(const s16x8*)(smB + 8192 + rb);
      if constexpr (NS >= 3) b2 = *(const s16x8*)(smB + 16384 + rb);
#pragma unroll
      for (int i = 0; i < 4; i++) {
        acc[i][j] = __builtin_amdgcn_mfma_f32_16x16x32_bf16(a0[i], b0, acc[i][j], 0, 0, 0);
        if constexpr (NS >= 2) {
          acc[i][j] = __builtin_amdgcn_mfma_f32_16x16x32_bf16(a0[i], b1, acc[i][j], 0, 0, 0);
          acc[i][j] = __builtin_amdgcn_mfma_f32_16x16x32_bf16(a1[i], b0, acc[i][j], 0, 0, 0);
        }
        if constexpr (NS >= 3) {
          acc[i][j] = __builtin_amdgcn_mfma_f32_16x16x32_bf16(a0[i], b2, acc[i][j], 0, 0, 0);
          acc[i][j] = __builtin_amdgcn_mfma_f32_16x16x32_bf16(a1[i], b1, acc[i][j], 0, 0, 0);
          acc[i][j] = __builtin_amdgcn_mfma_f32_16x16x32_bf16(a2[i], b0, acc[i][j], 0, 0, 0);
        }
      }
    }
    __syncthreads();
  }

  // ---- epilogue: C/D layout col=lane&15, row=(lane>>4)*4+r ----
  const int crow0 = wm * 64 + (l >> 4) * 4;
  const int ccol0 = wn * 64 + (l & 15);
#pragma unroll
  for (int i = 0; i < 4; i++)
#pragma unroll
    for (int j = 0; j < 4; j++)
#pragma unroll
      for (int r = 0; r < 4; r++) {
        const size_t row = brow + crow0 + i * 16 + r;
        const size_t col = bcol + ccol0 + j * 16;
        if constexpr (OUTBF) ((ushort*)Cp)[row * N + col] = f2bf(acc[i][j][r]);
        else                 ((float*)Cp)[row * N + col] = acc[i][j][r];
      }
}

// ---------------- weight transpose + split convert: W[K,N] -> T[N,K] ----------------
template<int NS>
__global__ __launch_bounds__(256) void tconv(const float* __restrict__ Wsrc,
                                             ushort* __restrict__ T0, ushort* __restrict__ T1,
                                             ushort* __restrict__ T2, int K, int N)
{
  __shared__ float t[32][33];
  const int kb = blockIdx.y * 32, nb = blockIdx.x * 32;
  const int tx = threadIdx.x & 31, ty = threadIdx.x >> 5;
#pragma unroll
  for (int i = 0; i < 32; i += 8)
    t[ty + i][tx] = Wsrc[(size_t)(kb + ty + i) * N + nb + tx];
  __syncthreads();
#pragma unroll
  for (int i = 0; i < 32; i += 8) {
    float v = t[tx][ty + i];
    size_t o = (size_t)(nb + ty + i) * K + kb + tx;
    ushort h = f2bf(v);
    T0[o] = h;
    if constexpr (NS >= 3) {
      float r1 = v - bf2f(h);
      ushort mm = f2bf(r1);
      T1[o] = mm;
      T2[o] = f2bf(r1 - bf2f(mm));
    }
  }
}

// ---------------- flat split3 convert ----------------
__global__ __launch_bounds__(256) void cvt3(const float* __restrict__ in,
                                            ushort* __restrict__ o0, ushort* __restrict__ o1,
                                            ushort* __restrict__ o2, int n)
{
  const int i = (blockIdx.x * 256 + threadIdx.x) * 4;
  if (i >= n) return;
  float4 v = *(const float4*)(in + i);
  float f[4] = {v.x, v.y, v.z, v.w};
  ushort4 u0, u1, u2;
  ushort* p0 = (ushort*)&u0; ushort* p1 = (ushort*)&u1; ushort* p2 = (ushort*)&u2;
#pragma unroll
  for (int e = 0; e < 4; e++) {
    ushort h = f2bf(f[e]);
    float r1 = f[e] - bf2f(h);
    ushort mm = f2bf(r1);
    p0[e] = h; p1[e] = mm; p2[e] = f2bf(r1 - bf2f(mm));
  }
  *(ushort4*)(o0 + i) = u0; *(ushort4*)(o1 + i) = u1; *(ushort4*)(o2 + i) = u2;
}

// ---------------- fused SiLU + LayerNorm -> bf16 (split3 or plain) ----------------
template<int NCOL, int NS>
__global__ __launch_bounds__(256) void silu_ln(const float* __restrict__ in,
                                               const float* __restrict__ g,
                                               const float* __restrict__ bta,
                                               ushort* __restrict__ o0, ushort* __restrict__ o1,
                                               ushort* __restrict__ o2)
{
  constexpr int PT = NCOL / 256;
  __shared__ float sb[256];
  const int b = blockIdx.x, t = threadIdx.x;
  const float* row = in + (size_t)b * NCOL;
  float v[PT];
  float s = 0.f;
#pragma unroll
  for (int i = 0; i < PT; i++) {
    float x = row[t + 256 * i];
    float sv = x / (1.f + expf(-x));
    v[i] = sv; s += sv;
  }
  s = blk_reduce_sum(s, sb);
  const float mu = s / (float)NCOL;
  float q = 0.f;
#pragma unroll
  for (int i = 0; i < PT; i++) { float d = v[i] - mu; q += d * d; }
  q = blk_reduce_sum(q, sb);
  const float inv = 1.f / sqrtf(q / (float)NCOL + 1e-5f);
#pragma unroll
  for (int i = 0; i < PT; i++) {
    const int c = t + 256 * i;
    const float y = (v[i] - mu) * inv * g[c] + bta[c];
    const size_t o = (size_t)b * NCOL + c;
    ushort h = f2bf(y);
    o0[o] = h;
    if constexpr (NS >= 3) {
      float r1 = y - bf2f(h);
      ushort mm = f2bf(r1);
      o1[o] = mm;
      o2[o] = f2bf(r1 - bf2f(mm));
    }
  }
}

// ---------------- codebook squared norms ----------------
__global__ __launch_bounds__(64) void colnorm2(const float* __restrict__ cb,
                                               float* __restrict__ cn2)
{
  const int r = blockIdx.x, t = threadIdx.x;
  const float* row = cb + (size_t)r * EMB;
  float s = 0.f;
#pragma unroll
  for (int i = 0; i < 4; i++) { float v = row[t + 64 * i]; s += v * v; }
  for (int off = 32; off > 0; off >>= 1) s += __shfl_down(s, off);
  if (t == 0) cn2[r] = s;
}

// ---------------- gumbel-max sampler (exact jax.random.categorical) ----------------
__global__ __launch_bounds__(256) void sampler(const float* __restrict__ S,
                                               const float* __restrict__ cn2,
                                               int* __restrict__ ids,
                                               uint32_t k0, uint32_t k1, int layer)
{
  __shared__ float sv[256];
  __shared__ int   si[256];
  const int b = blockIdx.x, t = threadIdx.x;
  const float* Srow = S + (size_t)b * KCB;
  float best = -INFINITY; int bestj = 0x7fffffff;
#pragma unroll
  for (int jj = 0; jj < 4; ++jj) {
    const int j = t + jj * 256;
    const uint32_t idx = (uint32_t)(b * KCB + j);
    uint32_t o0, o1;
    tf2x32(k0, k1, 0u, idx, o0, o1);
    uint32_t bits = o0 ^ o1;
    float f = __uint_as_float((bits >> 9) | 0x3f800000u) - 1.0f;
    float u = fmaxf(f, 1.17549435e-38f);
    float gmb = -logf(-logf(u));
    float logit = (2.0f * Srow[j] - cn2[j]) / 1.25f;
    float val = gmb + logit;
    if (val > best || (val == best && j < bestj)) { best = val; bestj = j; }
  }
  sv[t] = best; si[t] = bestj; __syncthreads();
  for (int s = 128; s > 0; s >>= 1) {
    if (t < s) {
      float v2 = sv[t + s]; int j2 = si[t + s];
      if (v2 > sv[t] || (v2 == sv[t] && j2 < si[t])) { sv[t] = v2; si[t] = j2; }
    }
    __syncthreads();
  }
  if (t == 0) ids[b * NLAYER + layer] = si[0];
}

// ---------------- rotation-trick quantize update ----------------
__global__ __launch_bounds__(256) void quant_update(float* __restrict__ res,
                                                    float* __restrict__ esum,
                                                    const float* __restrict__ cb,
                                                    const int* __restrict__ ids,
                                                    float* __restrict__ qrow,
                                                    float* __restrict__ outEn,
                                                    ushort* __restrict__ r0,
                                                    ushort* __restrict__ r1,
                                                    ushort* __restrict__ r2,
                                                    ushort* __restrict__ esumb,
                                                    int layer)
{
  __shared__ float sb[256];
  const int b = blockIdx.x, t = threadIdx.x;
  const size_t idx = (size_t)b * EMB + t;
  const float r = res[idx];
  const int id = ids[b * NLAYER + layer];
  const float e_ = cb[(size_t)id * EMB + t];

  const float rn2 = blk_reduce_sum(r * r, sb);
  const float en2 = blk_reduce_sum(e_ * e_, sb);
  const float rn = sqrtf(rn2), en = sqrtf(en2);
  const float u = r / (rn + 1e-8f);
  const float q = e_ / (en + 1e-8f);
  const float s = u + q;
  const float sn2 = blk_reduce_sum(s * s, sb);
  const float w = s / fmaxf(sqrtf(sn2), 1e-6f);
  const float rw = blk_reduce_sum(r * w, sb);
  const float ru = blk_reduce_sum(r * u, sb);
  const float e = r - 2.f * rw * w + 2.f * ru * q;
  const float eo2 = blk_reduce_sum(e * e, sb);
  const float dq = r - e_;
  const float ql = blk_reduce_sum(dq * dq, sb);

  if (t == 0) {
    outEn[b * NLAYER + layer] = sqrtf(eo2);
    if (layer == 0) qrow[b] = 1.25f * ql; else qrow[b] += 1.25f * ql;
  }
  const float nr = r - e;
  res[idx] = nr;
  // split3 of new residual for next distance GEMM
  {
    ushort h = f2bf(nr);
    float rr1 = nr - bf2f(h);
    ushort mm = f2bf(rr1);
    r0[idx] = h; r1[idx] = mm; r2[idx] = f2bf(rr1 - bf2f(mm));
  }
  float ns = (layer == 0) ? e : esum[idx] + e;
  esum[idx] = ns;
  if (layer == NLAYER - 1) esumb[idx] = f2bf(ns);
}

// ---------------- final l2norm + per-row recon (y in bf16) ----------------
__global__ __launch_bounds__(256) void l2norm_recon(const ushort* __restrict__ y,
                                                    const float* __restrict__ x,
                                                    float* __restrict__ recon)
{
  __shared__ float sb[256];
  const int b = blockIdx.x, t = threadIdx.x;
  const ushort* yr = y + (size_t)b * INDIM;
  const float* xr = x + (size_t)b * INDIM;
  s16x8 v = *(const s16x8*)&yr[t * 8];
  float vy[8];
  float ss = 0.f;
#pragma unroll
  for (int i = 0; i < 8; i++) { vy[i] = bf2f((ushort)v[i]); ss += vy[i] * vy[i]; }
  ss = blk_reduce_sum(ss, sb);
  const float inv = 1.f / fmaxf(sqrtf(ss), 1e-12f);
  float4 xa = *(const float4*)&xr[t * 8];
  float4 xb = *(const float4*)&xr[t * 8 + 4];
  float xf[8] = {xa.x, xa.y, xa.z, xa.w, xb.x, xb.y, xb.z, xb.w};
  float acc = 0.f;
#pragma unroll
  for (int i = 0; i < 8; i++) {
    float d = vy[i] * inv - xf[i];
    acc += d * d;
  }
  acc = blk_reduce_sum(acc, sb);
  if (t == 0) recon[b] = acc;
}

// ---------------- p_unique ----------------
__global__ __launch_bounds__(256) void pack_ids(const int* __restrict__ ids,
                                                uint32_t* __restrict__ packed)
{
  const int i = blockIdx.x * 256 + threadIdx.x;
  if (i < NB)
    packed[i] = (uint32_t)ids[i * 3] | ((uint32_t)ids[i * 3 + 1] << 10)
              | ((uint32_t)ids[i * 3 + 2] << 20);
}

__global__ __launch_bounds__(256) void unique_count(const uint32_t* __restrict__ packed,
                                                    int* __restrict__ part)
{
  __shared__ uint32_t sp[NB];
  __shared__ int sc[256];
  const int t = threadIdx.x;
  for (int i = t; i < NB; i += 256) sp[i] = packed[i];
  __syncthreads();
  const int row = blockIdx.x * 256 + t;
  int cnt = 0;
  {
    const uint32_t v = sp[row];
    bool dup = false;
    for (int j = row + 1; j < NB; j++) dup |= (sp[j] == v);
    cnt = dup ? 0 : 1;
  }
  sc[t] = cnt; __syncthreads();
  for (int s = 128; s > 0; s >>= 1) { if (t < s) sc[t] += sc[t + s]; __syncthreads(); }
  if (t == 0) part[blockIdx.x] = sc[0];
}

// ---------------- finalize scalars ----------------
__global__ __launch_bounds__(256) void finalize(const float* __restrict__ recon,
                                                const float* __restrict__ qrow,
                                                const int* __restrict__ upart,
                                                float* __restrict__ out)
{
  __shared__ double sd[256];
  __shared__ int si[256];
  const int t = threadIdx.x;
  double aR = 0.0, aQ = 0.0;
  for (int i = t; i < NB; i += 256) { aR += (double)recon[i]; aQ += (double)qrow[i]; }
  sd[t] = aR; __syncthreads();
  for (int s = 128; s > 0; s >>= 1) { if (t < s) sd[t] += sd[t + s]; __syncthreads(); }
  const double sumR = sd[0]; __syncthreads();
  sd[t] = aQ; __syncthreads();
  for (int s = 128; s > 0; s >>= 1) { if (t < s) sd[t] += sd[t + s]; __syncthreads(); }
  const double sumQ = sd[0]; __syncthreads();
  si[t] = (t < 32) ? upart[t] : 0; __syncthreads();
  for (int s = 128; s > 0; s >>= 1) { if (t < s) si[t] += si[t + s]; __syncthreads(); }
  if (t == 0) {
    const float rm = (float)(sumR / (double)NB);
    const float ql = (float)sumQ;
    out[0] = rm + ql;
    out[1] = rm;
    out[2] = ql;
    out[3 + NB * NLAYER] = (float)si[0] / (float)NB;
  }
}

// ---------------- host launch ----------------
extern "C" void kernel_launch(void* const* d_in, const int* in_sizes, int n_in,
                              void* d_out, int out_size, void* d_ws, size_t ws_size,
                              hipStream_t stream)
{
  const float* x      = (const float*)d_in[0];
  const float* enc_w1 = (const float*)d_in[1];
  const float* enc_g1 = (const float*)d_in[2];
  const float* enc_b1 = (const float*)d_in[3];
  const float* enc_w2 = (const float*)d_in[4];
  const float* enc_g2 = (const float*)d_in[5];
  const float* enc_b2 = (const float*)d_in[6];
  const float* enc_w3 = (const float*)d_in[7];
  const float* dec_w1 = (const float*)d_in[8];
  const float* dec_g1 = (const float*)d_in[9];
  const float* dec_b1 = (const float*)d_in[10];
  const float* dec_w2 = (const float*)d_in[11];
  const float* dec_g2 = (const float*)d_in[12];
  const float* dec_b2 = (const float*)d_in[13];
  const float* dec_w3 = (const float*)d_in[14];
  const float* codebooks = (const float*)d_in[15];
  float* out = (float*)d_out;

  char* W = (char*)d_ws;
  // region A (multi-use, 0..67108864)
  ushort* h1n0 = (ushort*)(W + 0);
  ushort* h1n1 = (ushort*)(W + 16777216);
  ushort* h1n2 = (ushort*)(W + 33554432);
  float*  h2   = (float*) (W + 50331648);
  ushort* h2n0 = (ushort*)(W + 0);
  ushort* h2n1 = (ushort*)(W + 8388608);
  ushort* h2n2 = (ushort*)(W + 16777216);
  float*  res32= (float*) (W + 25165824);
  ushort* res0 = (ushort*)(W + 33554432);
  ushort* res1 = (ushort*)(W + 37748736);
  ushort* res2 = (ushort*)(W + 41943040);
  float*  esum32=(float*) (W + 46137344);
  ushort* esumb =(ushort*)(W + 54525952);
  float*  d1    =(float*) (W + 0);
  ushort* d1nb  =(ushort*)(W + 16777216);
  ushort* d2nb  =(ushort*)(W + 25165824);
  // region B (67108864..100663296)
  float*  h1 = (float*)(W + 67108864);
  float*  S  = h1;
  float*  d2 = h1;
  ushort* yb = (ushort*)(W + 67108864);
  // weights region
  ushort* w1t0 = (ushort*)(W + 100663296);
  ushort* w1t1 = (ushort*)(W + 104857600);
  ushort* w1t2 = (ushort*)(W + 109051904);
  ushort* w2t0 = (ushort*)(W + 113246208);
  ushort* w2t1 = (ushort*)(W + 114294784);
  ushort* w2t2 = (ushort*)(W + 115343360);
  ushort* w3t0 = (ushort*)(W + 116391936);
  ushort* w3t1 = (ushort*)(W + 116654080);
  ushort* w3t2 = (ushort*)(W + 116916224);
  ushort* dw1t = (ushort*)(W + 117178368);
  ushort* dw2t = (ushort*)(W + 117440512);
  ushort* dw3t = (ushort*)(W + 118489088);
  ushort* cb0  = (ushort*)(W + 122683392);
  ushort* cb1  = (ushort*)(W + 124256256);
  ushort* cb2  = (ushort*)(W + 125829120);
  // misc
  float* cn2   = (float*)(W + 127401984);
  float* recon = (float*)(W + 127414272);
  float* qrow  = (float*)(W + 127447040);
  int*   ids   = (int*)  (W + 127479808);
  uint32_t* packed = (uint32_t*)(W + 127578112);
  int*   upart = (int*)  (W + 127610880);

  // PRNG keys: jax.random.split(jax.random.key(42), 3), partitionable scheme
  uint32_t key0[NLAYER], key1[NLAYER];
  for (int l = 0; l < NLAYER; l++) tf2x32(0u, 42u, 0u, (uint32_t)l, key0[l], key1[l]);

  dim3 blk(256);
  // ---- weight / codebook conversion ----
  tconv<3><<<dim3(H1N/32, INDIM/32), blk, 0, stream>>>(enc_w1, w1t0, w1t1, w1t2, INDIM, H1N);
  tconv<3><<<dim3(H2N/32, H1N/32), blk, 0, stream>>>(enc_w2, w2t0, w2t1, w2t2, H1N, H2N);
  tconv<3><<<dim3(EMB/32, H2N/32), blk, 0, stream>>>(enc_w3, w3t0, w3t1, w3t2, H2N, EMB);
  tconv<1><<<dim3(H2N/32, EMB/32), blk, 0, stream>>>(dec_w1, dw1t, nullptr, nullptr, EMB, H2N);
  tconv<1><<<dim3(H1N/32, H2N/32), blk, 0, stream>>>(dec_w2, dw2t, nullptr, nullptr, H2N, H1N);
  tconv<1><<<dim3(INDIM/32, H1N/32), blk, 0, stream>>>(dec_w3, dw3t, nullptr, nullptr, H1N, INDIM);
  cvt3<<<(NLAYER*KCB*EMB)/1024, blk, 0, stream>>>(codebooks, cb0, cb1, cb2, NLAYER*KCB*EMB);
  colnorm2<<<NLAYER*KCB, dim3(64), 0, stream>>>(codebooks, cn2);

  // ---- encoder ----
  mgemm<3,1,0><<<dim3(H1N/128, NB/128), blk, 0, stream>>>(x, nullptr, nullptr,
      w1t0, w1t1, w1t2, h1, NB, H1N, INDIM);
  silu_ln<H1N,3><<<NB, blk, 0, stream>>>(h1, enc_g1, enc_b1, h1n0, h1n1, h1n2);
  mgemm<3,0,0><<<dim3(H2N/128, NB/128), blk, 0, stream>>>(h1n0, h1n1, h1n2,
      w2t0, w2t1, w2t2, h2, NB, H2N, H1N);
  silu_ln<H2N,3><<<NB, blk, 0, stream>>>(h2, enc_g2, enc_b2, h2n0, h2n1, h2n2);
  mgemm<3,0,0><<<dim3(EMB/128, NB/128), blk, 0, stream>>>(h2n0, h2n1, h2n2,
      w3t0, w3t1, w3t2, res32, NB, EMB, H2N);
  cvt3<<<(NB*EMB)/1024, blk, 0, stream>>>(res32, res0, res1, res2, NB*EMB);

  // ---- quantization ----
  for (int l = 0; l < NLAYER; l++) {
    const float* cbl = codebooks + (size_t)l * KCB * EMB;
    const size_t co = (size_t)l * KCB * EMB;
    mgemm<3,0,0><<<dim3(KCB/128, NB/128), blk, 0, stream>>>(res0, res1, res2,
        cb0 + co, cb1 + co, cb2 + co, S, NB, KCB, EMB);
    sampler<<<NB, blk, 0, stream>>>(S, cn2 + l * KCB, ids, key0[l], key1[l], l);
    quant_update<<<NB, blk, 0, stream>>>(res32, esum32, cbl, ids, qrow, out + 3,
        res0, res1, res2, esumb, l);
  }

  // ---- decoder (plain bf16) ----
  mgemm<1,0,0><<<dim3(H2N/128, NB/128), blk, 0, stream>>>(esumb, nullptr, nullptr,
      dw1t, nullptr, nullptr, d1, NB, H2N, EMB);
  silu_ln<H2N,1><<<NB, blk, 0, stream>>>(d1, dec_g1, dec_b1, d1nb, nullptr, nullptr);
  mgemm<1,0,0><<<dim3(H1N/128, NB/128), blk, 0, stream>>>(d1nb, nullptr, nullptr,
      dw2t, nullptr, nullptr, d2, NB, H1N, H2N);
  silu_ln<H1N,1><<<NB, blk, 0, stream>>>(d2, dec_g2, dec_b2, d2nb, nullptr, nullptr);
  mgemm<1,0,1><<<dim3(INDIM/128, NB/128), blk, 0, stream>>>(d2nb, nullptr, nullptr,
      dw3t, nullptr, nullptr, yb, NB, INDIM, H1N);
  l2norm_recon<<<NB, blk, 0, stream>>>(yb, x, recon);

  // ---- p_unique + scalars ----
  pack_ids<<<NB/256, blk, 0, stream>>>(ids, packed);
  unique_count<<<NB/256, blk, 0, stream>>>(packed, upart);
  finalize<<<1, blk, 0, stream>>>(recon, qrow, upart, out);
}

// Round 3
// 925.517 us; speedup vs baseline: 2.0691x; 1.1664x over previous
//
#include <hip/hip_runtime.h>
#include <hip/hip_bf16.h>
#include <stdint.h>
#include <math.h>

// ---------------- problem constants ----------------
#define NB    8192
#define INDIM 2048
#define EMB   256
#define H1N   1024
#define H2N   512
#define KCB   1024
#define NLAYER 3

typedef _Float16 f16x8 __attribute__((ext_vector_type(8)));
typedef float    f32x4 __attribute__((ext_vector_type(4)));

#define LO_SCALE 1024.0f
#define LO_INV   (1.0f / 1024.0f)

#define GLD16(g, p) __builtin_amdgcn_global_load_lds( \
    (const __attribute__((address_space(1))) void*)(g), \
    (__attribute__((address_space(3))) void*)(p), 16, 0, 0)

// ---------------- threefry2x32 (20 rounds) ----------------
__host__ __device__ inline void tf2x32(uint32_t k0, uint32_t k1, uint32_t x0, uint32_t x1,
                                       uint32_t& o0, uint32_t& o1)
{
  const uint32_t ks2 = 0x1BD11BDAu ^ k0 ^ k1;
  uint32_t a = x0 + k0, b = x1 + k1;
#define TF_RND(r) { a += b; b = (b << (r)) | (b >> (32 - (r))); b ^= a; }
  TF_RND(13) TF_RND(15) TF_RND(26) TF_RND(6)
  a += k1; b += ks2 + 1u;
  TF_RND(17) TF_RND(29) TF_RND(16) TF_RND(24)
  a += ks2; b += k0 + 2u;
  TF_RND(13) TF_RND(15) TF_RND(26) TF_RND(6)
  a += k0; b += k1 + 3u;
  TF_RND(17) TF_RND(29) TF_RND(16) TF_RND(24)
  a += k1; b += ks2 + 4u;
  TF_RND(13) TF_RND(15) TF_RND(26) TF_RND(6)
  a += ks2; b += k0 + 5u;
#undef TF_RND
  o0 = a; o1 = b;
}

__device__ inline float blk_reduce_sum(float v, float* sbuf)
{
  const int t = threadIdx.x;
  sbuf[t] = v; __syncthreads();
  for (int s = 128; s > 0; s >>= 1) {
    if (t < s) sbuf[t] += sbuf[t + s];
    __syncthreads();
  }
  float r = sbuf[0];
  __syncthreads();
  return r;
}

// =================== MFMA GEMM (fp16, split-2) ===================
// C[M,N] = A[M,K] * B[N,K]^T.  A/B given as f16 hi (+ lo*1024 when NS==2).
// NS==2: acc0 += hi*hi; acc1 += hi*lo' + lo'*hi; C = acc0 + acc1/1024.
// OUTMODE: 0 = f32; 1 = f16 hi only; 2 = f32 + f16 split2 (Cs0/Cs1).
template<int NS, int OUTMODE>
__global__ __launch_bounds__(256) void mgemm(
    const _Float16* __restrict__ A0, const _Float16* __restrict__ A1,
    const _Float16* __restrict__ B0, const _Float16* __restrict__ B1,
    void* __restrict__ Cp, _Float16* __restrict__ Cs0, _Float16* __restrict__ Cs1,
    int M, int N, int K)
{
  constexpr int ABYTES = NS * 8192;
  constexpr int SMB = 2 * ABYTES;
  __shared__ __align__(16) char sm[SMB];
  char* smA = sm;
  char* smB = sm + ABYTES;

  const int tid = threadIdx.x;
  const int w = tid >> 6, l = tid & 63;
  const int wm = w >> 1, wn = w & 1;
  const size_t brow = (size_t)blockIdx.y * 128;
  const size_t bcol = (size_t)blockIdx.x * 128;

  // staging (pre-swizzled global source; linear LDS dest)
  const int brow16 = w * 16 + (l >> 2);
  const int bcol16 = ((l & 3) ^ ((l >> 3) & 3)) * 8;

  const _Float16* gA0 = A0 + (brow + brow16) * (size_t)K + bcol16;
  const _Float16* gA1 = (NS >= 2) ? (A1 + (brow + brow16) * (size_t)K + bcol16) : nullptr;
  const _Float16* gB0 = B0 + (bcol + brow16) * (size_t)K + bcol16;
  const _Float16* gB1 = (NS >= 2) ? (B1 + (bcol + brow16) * (size_t)K + bcol16) : nullptr;

  f32x4 acc0[4][4], acc1[4][4];
#pragma unroll
  for (int i = 0; i < 4; i++)
#pragma unroll
    for (int j = 0; j < 4; j++) {
      acc0[i][j] = (f32x4){0.f, 0.f, 0.f, 0.f};
      if constexpr (NS >= 2) acc1[i][j] = (f32x4){0.f, 0.f, 0.f, 0.f};
    }

  const int srow = l & 15;
  const int ksel = l >> 4;
  const int sel2 = (srow >> 1) & 3;
  const int fslot16 = (ksel ^ sel2) * 16;

  for (int k0 = 0; k0 < K; k0 += 32) {
#pragma unroll
    for (int i = 0; i < 2; i++) {
      GLD16(gA0 + (size_t)(i * 64) * K + k0, smA + i * 4096 + w * 1024);
      if constexpr (NS >= 2) GLD16(gA1 + (size_t)(i * 64) * K + k0, smA + 8192 + i * 4096 + w * 1024);
      GLD16(gB0 + (size_t)(i * 64) * K + k0, smB + i * 4096 + w * 1024);
      if constexpr (NS >= 2) GLD16(gB1 + (size_t)(i * 64) * K + k0, smB + 8192 + i * 4096 + w * 1024);
    }
    __syncthreads();

    f16x8 ah[4], al[4];
#pragma unroll
    for (int i = 0; i < 4; i++) {
      const int rb = (wm * 64 + i * 16 + srow) * 64 + fslot16;
      ah[i] = *(const f16x8*)(smA + rb);
      if constexpr (NS >= 2) al[i] = *(const f16x8*)(smA + 8192 + rb);
    }

#pragma unroll
    for (int j = 0; j < 4; j++) {
      const int rb = (wn * 64 + j * 16 + srow) * 64 + fslot16;
      f16x8 bh = *(const f16x8*)(smB + rb);
      f16x8 bl{};
      if constexpr (NS >= 2) bl = *(const f16x8*)(smB + 8192 + rb);
#pragma unroll
      for (int i = 0; i < 4; i++) {
        acc0[i][j] = __builtin_amdgcn_mfma_f32_16x16x32_f16(ah[i], bh, acc0[i][j], 0, 0, 0);
        if constexpr (NS >= 2) {
          acc1[i][j] = __builtin_amdgcn_mfma_f32_16x16x32_f16(ah[i], bl, acc1[i][j], 0, 0, 0);
          acc1[i][j] = __builtin_amdgcn_mfma_f32_16x16x32_f16(al[i], bh, acc1[i][j], 0, 0, 0);
        }
      }
    }
    __syncthreads();
  }

  // ---- epilogue: C/D layout col=lane&15, row=(lane>>4)*4+r ----
  const int crow0 = wm * 64 + (l >> 4) * 4;
  const int ccol0 = wn * 64 + (l & 15);
#pragma unroll
  for (int i = 0; i < 4; i++)
#pragma unroll
    for (int j = 0; j < 4; j++)
#pragma unroll
      for (int r = 0; r < 4; r++) {
        float v = acc0[i][j][r];
        if constexpr (NS >= 2) v += acc1[i][j][r] * LO_INV;
        const size_t row = brow + crow0 + i * 16 + r;
        const size_t col = bcol + ccol0 + j * 16;
        const size_t o = row * N + col;
        if constexpr (OUTMODE == 0) {
          ((float*)Cp)[o] = v;
        } else if constexpr (OUTMODE == 1) {
          ((_Float16*)Cp)[o] = (_Float16)v;
        } else {
          ((float*)Cp)[o] = v;
          _Float16 h = (_Float16)v;
          Cs0[o] = h;
          Cs1[o] = (_Float16)((v - (float)h) * LO_SCALE);
        }
      }
}

// ---------------- weight transpose + split convert: W[K,N] -> T[N,K] f16 ----------------
template<int NS>
__global__ __launch_bounds__(256) void tconv(const float* __restrict__ Wsrc,
                                             _Float16* __restrict__ T0,
                                             _Float16* __restrict__ T1, int K, int N)
{
  __shared__ float t[32][33];
  const int kb = blockIdx.y * 32, nb = blockIdx.x * 32;
  const int tx = threadIdx.x & 31, ty = threadIdx.x >> 5;
#pragma unroll
  for (int i = 0; i < 32; i += 8)
    t[ty + i][tx] = Wsrc[(size_t)(kb + ty + i) * N + nb + tx];
  __syncthreads();
#pragma unroll
  for (int i = 0; i < 32; i += 8) {
    float v = t[tx][ty + i];
    size_t o = (size_t)(nb + ty + i) * K + kb + tx;
    _Float16 h = (_Float16)v;
    T0[o] = h;
    if constexpr (NS >= 2) T1[o] = (_Float16)((v - (float)h) * LO_SCALE);
  }
}

// ---------------- flat f32 -> f16 split2 (8 elems/thread) ----------------
__global__ __launch_bounds__(256) void cvt2(const float* __restrict__ in,
                                            _Float16* __restrict__ oh,
                                            _Float16* __restrict__ ol, int n)
{
  const int i = (blockIdx.x * 256 + threadIdx.x) * 8;
  if (i >= n) return;
  float4 va = *(const float4*)(in + i);
  float4 vb = *(const float4*)(in + i + 4);
  float f[8] = {va.x, va.y, va.z, va.w, vb.x, vb.y, vb.z, vb.w};
  f16x8 hv, lv;
#pragma unroll
  for (int e = 0; e < 8; e++) {
    _Float16 h = (_Float16)f[e];
    hv[e] = h;
    lv[e] = (_Float16)((f[e] - (float)h) * LO_SCALE);
  }
  *(f16x8*)(oh + i) = hv;
  *(f16x8*)(ol + i) = lv;
}

// ---------------- codebook: split convert + squared norms ----------------
__global__ __launch_bounds__(256) void cbconv(const float* __restrict__ cb,
                                              _Float16* __restrict__ ch,
                                              _Float16* __restrict__ cl,
                                              float* __restrict__ cn2)
{
  __shared__ float sb[256];
  const int r = blockIdx.x, t = threadIdx.x;
  const size_t o = (size_t)r * EMB + t;
  const float v = cb[o];
  _Float16 h = (_Float16)v;
  ch[o] = h;
  cl[o] = (_Float16)((v - (float)h) * LO_SCALE);
  float s = blk_reduce_sum(v * v, sb);
  if (t == 0) cn2[r] = s;
}

// ---------------- fused SiLU + LayerNorm -> f16 (split2 or plain) ----------------
template<int NCOL, int NS>
__global__ __launch_bounds__(256) void silu_ln(const float* __restrict__ in,
                                               const float* __restrict__ g,
                                               const float* __restrict__ bta,
                                               _Float16* __restrict__ o0,
                                               _Float16* __restrict__ o1)
{
  constexpr int PT = NCOL / 256;
  __shared__ float sb[256];
  const int b = blockIdx.x, t = threadIdx.x;
  const float* row = in + (size_t)b * NCOL;
  float v[PT];
  float s = 0.f;
#pragma unroll
  for (int i = 0; i < PT; i++) {
    float x = row[t + 256 * i];
    float sv = x / (1.f + expf(-x));
    v[i] = sv; s += sv;
  }
  s = blk_reduce_sum(s, sb);
  const float mu = s / (float)NCOL;
  float q = 0.f;
#pragma unroll
  for (int i = 0; i < PT; i++) { float d = v[i] - mu; q += d * d; }
  q = blk_reduce_sum(q, sb);
  const float inv = 1.f / sqrtf(q / (float)NCOL + 1e-5f);
#pragma unroll
  for (int i = 0; i < PT; i++) {
    const int c = t + 256 * i;
    const float y = (v[i] - mu) * inv * g[c] + bta[c];
    const size_t o = (size_t)b * NCOL + c;
    _Float16 h = (_Float16)y;
    o0[o] = h;
    if constexpr (NS >= 2) o1[o] = (_Float16)((y - (float)h) * LO_SCALE);
  }
}

// ---------------- fused gumbel-max sampler + rotation-trick update ----------------
__global__ __launch_bounds__(256) void sample_update(
    const float* __restrict__ S, const float* __restrict__ cn2l,
    const float* __restrict__ cbf,
    float* __restrict__ res, float* __restrict__ esum,
    float* __restrict__ qrow, float* __restrict__ outEn,
    _Float16* __restrict__ r0, _Float16* __restrict__ r1,
    _Float16* __restrict__ esumb, int* __restrict__ ids,
    uint32_t k0, uint32_t k1, int layer)
{
  __shared__ float sv[256];
  __shared__ int   si[256];
  const int b = blockIdx.x, t = threadIdx.x;
  const float* Srow = S + (size_t)b * KCB;

  // --- sampler phase (exact jax.random.categorical via gumbel-max) ---
  float best = -INFINITY; int bestj = 0x7fffffff;
#pragma unroll
  for (int jj = 0; jj < 4; ++jj) {
    const int j = t + jj * 256;
    const uint32_t idx = (uint32_t)(b * KCB + j);
    uint32_t o0, o1;
    tf2x32(k0, k1, 0u, idx, o0, o1);
    uint32_t bits = o0 ^ o1;
    float f = __uint_as_float((bits >> 9) | 0x3f800000u) - 1.0f;
    float u = fmaxf(f, 1.17549435e-38f);
    float gmb = -__logf(-__logf(u));
    float logit = (2.0f * Srow[j] - cn2l[j]) / 1.25f;
    float val = gmb + logit;
    if (val > best || (val == best && j < bestj)) { best = val; bestj = j; }
  }
  sv[t] = best; si[t] = bestj; __syncthreads();
  for (int s = 128; s > 0; s >>= 1) {
    if (t < s) {
      float v2 = sv[t + s]; int j2 = si[t + s];
      if (v2 > sv[t] || (v2 == sv[t] && j2 < si[t])) { sv[t] = v2; si[t] = j2; }
    }
    __syncthreads();
  }
  const int id = si[0];
  if (t == 0) ids[b * NLAYER + layer] = id;
  __syncthreads();

  // --- rotation-trick update phase ---
  const size_t idx = (size_t)b * EMB + t;
  const float r = res[idx];
  const float e_ = cbf[(size_t)id * EMB + t];

  const float rn2 = blk_reduce_sum(r * r, sv);
  const float en2 = blk_reduce_sum(e_ * e_, sv);
  const float rn = sqrtf(rn2), en = sqrtf(en2);
  const float u = r / (rn + 1e-8f);
  const float q = e_ / (en + 1e-8f);
  const float sm = u + q;
  const float sn2 = blk_reduce_sum(sm * sm, sv);
  const float w = sm / fmaxf(sqrtf(sn2), 1e-6f);
  const float rw = blk_reduce_sum(r * w, sv);
  const float ru = blk_reduce_sum(r * u, sv);
  const float e = r - 2.f * rw * w + 2.f * ru * q;
  const float eo2 = blk_reduce_sum(e * e, sv);
  const float dq = r - e_;
  const float ql = blk_reduce_sum(dq * dq, sv);

  if (t == 0) {
    outEn[b * NLAYER + layer] = sqrtf(eo2);
    if (layer == 0) qrow[b] = 1.25f * ql; else qrow[b] += 1.25f * ql;
  }
  const float nr = r - e;
  res[idx] = nr;
  {
    _Float16 h = (_Float16)nr;
    r0[idx] = h;
    r1[idx] = (_Float16)((nr - (float)h) * LO_SCALE);
  }
  float ns = (layer == 0) ? e : esum[idx] + e;
  esum[idx] = ns;
  if (layer == NLAYER - 1) esumb[idx] = (_Float16)ns;
}

// ---------------- final l2norm + per-row recon (y in f16) ----------------
__global__ __launch_bounds__(256) void l2norm_recon(const _Float16* __restrict__ y,
                                                    const float* __restrict__ x,
                                                    float* __restrict__ recon)
{
  __shared__ float sb[256];
  const int b = blockIdx.x, t = threadIdx.x;
  const _Float16* yr = y + (size_t)b * INDIM;
  const float* xr = x + (size_t)b * INDIM;
  f16x8 v = *(const f16x8*)&yr[t * 8];
  float vy[8];
  float ss = 0.f;
#pragma unroll
  for (int i = 0; i < 8; i++) { vy[i] = (float)v[i]; ss += vy[i] * vy[i]; }
  ss = blk_reduce_sum(ss, sb);
  const float inv = 1.f / fmaxf(sqrtf(ss), 1e-12f);
  float4 xa = *(const float4*)&xr[t * 8];
  float4 xb = *(const float4*)&xr[t * 8 + 4];
  float xf[8] = {xa.x, xa.y, xa.z, xa.w, xb.x, xb.y, xb.z, xb.w};
  float acc = 0.f;
#pragma unroll
  for (int i = 0; i < 8; i++) {
    float d = vy[i] * inv - xf[i];
    acc += d * d;
  }
  acc = blk_reduce_sum(acc, sb);
  if (t == 0) recon[b] = acc;
}

// ---------------- p_unique ----------------
__global__ __launch_bounds__(256) void pack_ids(const int* __restrict__ ids,
                                                uint32_t* __restrict__ packed)
{
  const int i = blockIdx.x * 256 + threadIdx.x;
  if (i < NB)
    packed[i] = (uint32_t)ids[i * 3] | ((uint32_t)ids[i * 3 + 1] << 10)
              | ((uint32_t)ids[i * 3 + 2] << 20);
}

__global__ __launch_bounds__(256) void unique_count(const uint32_t* __restrict__ packed,
                                                    int* __restrict__ part)
{
  __shared__ uint32_t sp[NB];
  __shared__ int sc[256];
  const int t = threadIdx.x;
  for (int i = t; i < NB; i += 256) sp[i] = packed[i];
  __syncthreads();
  const int row = blockIdx.x * 256 + t;
  int cnt = 0;
  {
    const uint32_t v = sp[row];
    bool dup = false;
    for (int j = row + 1; j < NB; j++) dup |= (sp[j] == v);
    cnt = dup ? 0 : 1;
  }
  sc[t] = cnt; __syncthreads();
  for (int s = 128; s > 0; s >>= 1) { if (t < s) sc[t] += sc[t + s]; __syncthreads(); }
  if (t == 0) part[blockIdx.x] = sc[0];
}

// ---------------- finalize scalars ----------------
__global__ __launch_bounds__(256) void finalize(const float* __restrict__ recon,
                                                const float* __restrict__ qrow,
                                                const int* __restrict__ upart,
                                                float* __restrict__ out)
{
  __shared__ double sd[256];
  __shared__ int si[256];
  const int t = threadIdx.x;
  double aR = 0.0, aQ = 0.0;
  for (int i = t; i < NB; i += 256) { aR += (double)recon[i]; aQ += (double)qrow[i]; }
  sd[t] = aR; __syncthreads();
  for (int s = 128; s > 0; s >>= 1) { if (t < s) sd[t] += sd[t + s]; __syncthreads(); }
  const double sumR = sd[0]; __syncthreads();
  sd[t] = aQ; __syncthreads();
  for (int s = 128; s > 0; s >>= 1) { if (t < s) sd[t] += sd[t + s]; __syncthreads(); }
  const double sumQ = sd[0]; __syncthreads();
  si[t] = (t < 32) ? upart[t] : 0; __syncthreads();
  for (int s = 128; s > 0; s >>= 1) { if (t < s) si[t] += si[t + s]; __syncthreads(); }
  if (t == 0) {
    const float rm = (float)(sumR / (double)NB);
    const float ql = (float)sumQ;
    out[0] = rm + ql;
    out[1] = rm;
    out[2] = ql;
    out[3 + NB * NLAYER] = (float)si[0] / (float)NB;
  }
}

// ---------------- host launch ----------------
extern "C" void kernel_launch(void* const* d_in, const int* in_sizes, int n_in,
                              void* d_out, int out_size, void* d_ws, size_t ws_size,
                              hipStream_t stream)
{
  const float* x      = (const float*)d_in[0];
  const float* enc_w1 = (const float*)d_in[1];
  const float* enc_g1 = (const float*)d_in[2];
  const float* enc_b1 = (const float*)d_in[3];
  const float* enc_w2 = (const float*)d_in[4];
  const float* enc_g2 = (const float*)d_in[5];
  const float* enc_b2 = (const float*)d_in[6];
  const float* enc_w3 = (const float*)d_in[7];
  const float* dec_w1 = (const float*)d_in[8];
  const float* dec_g1 = (const float*)d_in[9];
  const float* dec_b1 = (const float*)d_in[10];
  const float* dec_w2 = (const float*)d_in[11];
  const float* dec_g2 = (const float*)d_in[12];
  const float* dec_b2 = (const float*)d_in[13];
  const float* dec_w3 = (const float*)d_in[14];
  const float* codebooks = (const float*)d_in[15];
  float* out = (float*)d_out;

  char* W = (char*)d_ws;
  // region [0,32MB): xh -> h1n0/h1n1 -> h2n0/h2n1 + res0/res1 -> d1n/d2n
  _Float16* xh   = (_Float16*)(W + 0);          // 32MB, dies after enc1
  _Float16* h1n0 = (_Float16*)(W + 0);          // 16MB
  _Float16* h1n1 = (_Float16*)(W + 16777216);   // 16MB
  _Float16* h2n0 = (_Float16*)(W + 0);          // 8MB
  _Float16* h2n1 = (_Float16*)(W + 8388608);    // 8MB
  _Float16* res0 = (_Float16*)(W + 16777216);   // 4MB  (lives through quant loop)
  _Float16* res1 = (_Float16*)(W + 20971520);   // 4MB
  _Float16* d1n  = (_Float16*)(W + 0);          // 8MB (decoder phase)
  _Float16* d2n  = (_Float16*)(W + 25165824);   // 16MB [24,40)
  // region [32,64MB): xl -> h2 f32 / d1 f32 ; res32/esum32 at top
  _Float16* xl    = (_Float16*)(W + 33554432);  // 32MB, dies after enc1
  float*    h2    = (float*)  (W + 33554432);   // 16MB
  float*    d1    = (float*)  (W + 33554432);   // 16MB
  float*    res32 = (float*)  (W + 50331648);   // 8MB
  float*    esum32= (float*)  (W + 58720256);   // 8MB
  // region [64,96MB): h1 f32 -> S -> d2 f32 -> y f16
  float*    h1 = (float*)    (W + 67108864);    // 32MB
  float*    S  = (float*)    (W + 67108864);    // 32MB
  float*    d2 = (float*)    (W + 67108864);    // 32MB
  _Float16* yb = (_Float16*) (W + 67108864);    // 32MB
  // weights region [96MB+)
  _Float16* w1t0 = (_Float16*)(W + 100663296);  // 4MB
  _Float16* w1t1 = (_Float16*)(W + 104857600);  // 4MB
  _Float16* w2t0 = (_Float16*)(W + 109051904);  // 1MB
  _Float16* w2t1 = (_Float16*)(W + 110100480);  // 1MB
  _Float16* w3t0 = (_Float16*)(W + 111149056);  // 256KB
  _Float16* w3t1 = (_Float16*)(W + 111411200);  // 256KB
  _Float16* dw1t = (_Float16*)(W + 111673344);  // 256KB
  _Float16* dw2t = (_Float16*)(W + 111935488);  // 1MB
  _Float16* dw3t = (_Float16*)(W + 112984064);  // 4MB
  _Float16* cbh  = (_Float16*)(W + 117178368);  // 1.5MB
  _Float16* cbl  = (_Float16*)(W + 118751232);  // 1.5MB
  _Float16* esumb= (_Float16*)(W + 120324096);  // 4MB
  float* cn2   = (float*)(W + 124518400);
  float* recon = (float*)(W + 124534784);
  float* qrow  = (float*)(W + 124567552);
  int*   ids   = (int*)  (W + 124600320);
  uint32_t* packed = (uint32_t*)(W + 124698624);
  int*   upart = (int*)  (W + 124731392);

  // PRNG keys: jax.random.split(jax.random.key(42), 3), partitionable scheme
  uint32_t key0[NLAYER], key1[NLAYER];
  for (int l = 0; l < NLAYER; l++) tf2x32(0u, 42u, 0u, (uint32_t)l, key0[l], key1[l]);

  dim3 blk(256);
  // ---- weight / input / codebook conversion ----
  tconv<2><<<dim3(H1N/32, INDIM/32), blk, 0, stream>>>(enc_w1, w1t0, w1t1, INDIM, H1N);
  tconv<2><<<dim3(H2N/32, H1N/32), blk, 0, stream>>>(enc_w2, w2t0, w2t1, H1N, H2N);
  tconv<2><<<dim3(EMB/32, H2N/32), blk, 0, stream>>>(enc_w3, w3t0, w3t1, H2N, EMB);
  tconv<1><<<dim3(H2N/32, EMB/32), blk, 0, stream>>>(dec_w1, dw1t, nullptr, EMB, H2N);
  tconv<1><<<dim3(H1N/32, H2N/32), blk, 0, stream>>>(dec_w2, dw2t, nullptr, H2N, H1N);
  tconv<1><<<dim3(INDIM/32, H1N/32), blk, 0, stream>>>(dec_w3, dw3t, nullptr, H1N, INDIM);
  cvt2<<<(NB*INDIM)/2048, blk, 0, stream>>>(x, xh, xl, NB*INDIM);
  cbconv<<<NLAYER*KCB, blk, 0, stream>>>(codebooks, cbh, cbl, cn2);

  // ---- encoder (f16 split2, fp32-class) ----
  mgemm<2,0><<<dim3(H1N/128, NB/128), blk, 0, stream>>>(xh, xl, w1t0, w1t1,
      h1, nullptr, nullptr, NB, H1N, INDIM);
  silu_ln<H1N,2><<<NB, blk, 0, stream>>>(h1, enc_g1, enc_b1, h1n0, h1n1);
  mgemm<2,0><<<dim3(H2N/128, NB/128), blk, 0, stream>>>(h1n0, h1n1, w2t0, w2t1,
      h2, nullptr, nullptr, NB, H2N, H1N);
  silu_ln<H2N,2><<<NB, blk, 0, stream>>>(h2, enc_g2, enc_b2, h2n0, h2n1);
  mgemm<2,2><<<dim3(EMB/128, NB/128), blk, 0, stream>>>(h2n0, h2n1, w3t0, w3t1,
      res32, res0, res1, NB, EMB, H2N);

  // ---- quantization ----
  for (int l = 0; l < NLAYER; l++) {
    const float* cbfl = codebooks + (size_t)l * KCB * EMB;
    const size_t co = (size_t)l * KCB * EMB;
    mgemm<2,0><<<dim3(KCB/128, NB/128), blk, 0, stream>>>(res0, res1,
        cbh + co, cbl + co, S, nullptr, nullptr, NB, KCB, EMB);
    sample_update<<<NB, blk, 0, stream>>>(S, cn2 + l * KCB, cbfl,
        res32, esum32, qrow, out + 3, res0, res1, esumb, ids, key0[l], key1[l], l);
  }

  // ---- decoder (f16 single product) ----
  mgemm<1,0><<<dim3(H2N/128, NB/128), blk, 0, stream>>>(esumb, nullptr, dw1t, nullptr,
      d1, nullptr, nullptr, NB, H2N, EMB);
  silu_ln<H2N,1><<<NB, blk, 0, stream>>>(d1, dec_g1, dec_b1, d1n, nullptr);
  mgemm<1,0><<<dim3(H1N/128, NB/128), blk, 0, stream>>>(d1n, nullptr, dw2t, nullptr,
      d2, nullptr, nullptr, NB, H1N, H2N);
  silu_ln<H1N,1><<<NB, blk, 0, stream>>>(d2, dec_g2, dec_b2, d2n, nullptr);
  mgemm<1,1><<<dim3(INDIM/128, NB/128), blk, 0, stream>>>(d2n, nullptr, dw3t, nullptr,
      yb, nullptr, nullptr, NB, INDIM, H1N);
  l2norm_recon<<<NB, blk, 0, stream>>>(yb, x, recon);

  // ---- p_unique + scalars ----
  pack_ids<<<NB/256, blk, 0, stream>>>(ids, packed);
  unique_count<<<NB/256, blk, 0, stream>>>(packed, upart);
  finalize<<<1, blk, 0, stream>>>(recon, qrow, upart, out);
}

// Round 4
// 694.855 us; speedup vs baseline: 2.7559x; 1.3320x over previous
//
#include <hip/hip_runtime.h>
#include <hip/hip_bf16.h>
#include <stdint.h>
#include <math.h>

// ---------------- problem constants ----------------
#define NB    8192
#define INDIM 2048
#define EMB   256
#define H1N   1024
#define H2N   512
#define KCB   1024
#define NLAYER 3
#define HASHN 16384

typedef _Float16 f16x8 __attribute__((ext_vector_type(8)));
typedef float    f32x4 __attribute__((ext_vector_type(4)));

#define LO_SCALE 1024.0f
#define LO_INV   (1.0f / 1024.0f)

#define GLD16(g, p) __builtin_amdgcn_global_load_lds( \
    (const __attribute__((address_space(1))) void*)(g), \
    (__attribute__((address_space(3))) void*)(p), 16, 0, 0)

// ---------------- threefry2x32 (20 rounds) ----------------
__host__ __device__ inline void tf2x32(uint32_t k0, uint32_t k1, uint32_t x0, uint32_t x1,
                                       uint32_t& o0, uint32_t& o1)
{
  const uint32_t ks2 = 0x1BD11BDAu ^ k0 ^ k1;
  uint32_t a = x0 + k0, b = x1 + k1;
#define TF_RND(r) { a += b; b = (b << (r)) | (b >> (32 - (r))); b ^= a; }
  TF_RND(13) TF_RND(15) TF_RND(26) TF_RND(6)
  a += k1; b += ks2 + 1u;
  TF_RND(17) TF_RND(29) TF_RND(16) TF_RND(24)
  a += ks2; b += k0 + 2u;
  TF_RND(13) TF_RND(15) TF_RND(26) TF_RND(6)
  a += k0; b += k1 + 3u;
  TF_RND(17) TF_RND(29) TF_RND(16) TF_RND(24)
  a += k1; b += ks2 + 4u;
  TF_RND(13) TF_RND(15) TF_RND(26) TF_RND(6)
  a += ks2; b += k0 + 5u;
#undef TF_RND
  o0 = a; o1 = b;
}

__device__ inline float blk_reduce_sum(float v, float* sbuf)
{
  const int t = threadIdx.x;
  sbuf[t] = v; __syncthreads();
  for (int s = 128; s > 0; s >>= 1) {
    if (t < s) sbuf[t] += sbuf[t + s];
    __syncthreads();
  }
  float r = sbuf[0];
  __syncthreads();
  return r;
}

// =================== MFMA GEMM (fp16, split-2) ===================
// C[M,N] = A[M,K] * B[N,K]^T.  A/B given as f16 hi (+ lo*1024 when NS==2).
// NS==2: acc0 += hi*hi; acc1 += hi*lo' + lo'*hi; C = acc0 + acc1/1024.
// OUTMODE: 0 = f32; 1 = f16 hi only; 2 = f32 + f16 split2 (Cs0/Cs1).
template<int NS, int OUTMODE>
__global__ __launch_bounds__(256) void mgemm(
    const _Float16* __restrict__ A0, const _Float16* __restrict__ A1,
    const _Float16* __restrict__ B0, const _Float16* __restrict__ B1,
    void* __restrict__ Cp, _Float16* __restrict__ Cs0, _Float16* __restrict__ Cs1,
    int M, int N, int K)
{
  constexpr int ABYTES = NS * 8192;
  constexpr int SMB = 2 * ABYTES;
  __shared__ __align__(16) char sm[SMB];
  char* smA = sm;
  char* smB = sm + ABYTES;

  // XCD-aware bijective swizzle (all grids here have nwg % 8 == 0)
  const int nwg = gridDim.x * gridDim.y;
  const int bid0 = blockIdx.y * gridDim.x + blockIdx.x;
  const int cpx = nwg >> 3;
  const int swz = (bid0 & 7) * cpx + (bid0 >> 3);
  const int bx = swz % gridDim.x, by = swz / gridDim.x;

  const int tid = threadIdx.x;
  const int w = tid >> 6, l = tid & 63;
  const int wm = w >> 1, wn = w & 1;
  const size_t brow = (size_t)by * 128;
  const size_t bcol = (size_t)bx * 128;

  // staging (pre-swizzled global source; linear LDS dest)
  const int brow16 = w * 16 + (l >> 2);
  const int bcol16 = ((l & 3) ^ ((l >> 3) & 3)) * 8;

  const _Float16* gA0 = A0 + (brow + brow16) * (size_t)K + bcol16;
  const _Float16* gA1 = (NS >= 2) ? (A1 + (brow + brow16) * (size_t)K + bcol16) : nullptr;
  const _Float16* gB0 = B0 + (bcol + brow16) * (size_t)K + bcol16;
  const _Float16* gB1 = (NS >= 2) ? (B1 + (bcol + brow16) * (size_t)K + bcol16) : nullptr;

  f32x4 acc0[4][4], acc1[4][4];
#pragma unroll
  for (int i = 0; i < 4; i++)
#pragma unroll
    for (int j = 0; j < 4; j++) {
      acc0[i][j] = (f32x4){0.f, 0.f, 0.f, 0.f};
      if constexpr (NS >= 2) acc1[i][j] = (f32x4){0.f, 0.f, 0.f, 0.f};
    }

  const int srow = l & 15;
  const int ksel = l >> 4;
  const int sel2 = (srow >> 1) & 3;
  const int fslot16 = (ksel ^ sel2) * 16;

  for (int k0 = 0; k0 < K; k0 += 32) {
#pragma unroll
    for (int i = 0; i < 2; i++) {
      GLD16(gA0 + (size_t)(i * 64) * K + k0, smA + i * 4096 + w * 1024);
      if constexpr (NS >= 2) GLD16(gA1 + (size_t)(i * 64) * K + k0, smA + 8192 + i * 4096 + w * 1024);
      GLD16(gB0 + (size_t)(i * 64) * K + k0, smB + i * 4096 + w * 1024);
      if constexpr (NS >= 2) GLD16(gB1 + (size_t)(i * 64) * K + k0, smB + 8192 + i * 4096 + w * 1024);
    }
    __syncthreads();

    f16x8 ah[4], al[4];
#pragma unroll
    for (int i = 0; i < 4; i++) {
      const int rb = (wm * 64 + i * 16 + srow) * 64 + fslot16;
      ah[i] = *(const f16x8*)(smA + rb);
      if constexpr (NS >= 2) al[i] = *(const f16x8*)(smA + 8192 + rb);
    }

#pragma unroll
    for (int j = 0; j < 4; j++) {
      const int rb = (wn * 64 + j * 16 + srow) * 64 + fslot16;
      f16x8 bh = *(const f16x8*)(smB + rb);
      f16x8 bl{};
      if constexpr (NS >= 2) bl = *(const f16x8*)(smB + 8192 + rb);
#pragma unroll
      for (int i = 0; i < 4; i++) {
        acc0[i][j] = __builtin_amdgcn_mfma_f32_16x16x32_f16(ah[i], bh, acc0[i][j], 0, 0, 0);
        if constexpr (NS >= 2) {
          acc1[i][j] = __builtin_amdgcn_mfma_f32_16x16x32_f16(ah[i], bl, acc1[i][j], 0, 0, 0);
          acc1[i][j] = __builtin_amdgcn_mfma_f32_16x16x32_f16(al[i], bh, acc1[i][j], 0, 0, 0);
        }
      }
    }
    __syncthreads();
  }

  // ---- epilogue: C/D layout col=lane&15, row=(lane>>4)*4+r ----
  const int crow0 = wm * 64 + (l >> 4) * 4;
  const int ccol0 = wn * 64 + (l & 15);
#pragma unroll
  for (int i = 0; i < 4; i++)
#pragma unroll
    for (int j = 0; j < 4; j++)
#pragma unroll
      for (int r = 0; r < 4; r++) {
        float v = acc0[i][j][r];
        if constexpr (NS >= 2) v += acc1[i][j][r] * LO_INV;
        const size_t row = brow + crow0 + i * 16 + r;
        const size_t col = bcol + ccol0 + j * 16;
        const size_t o = row * N + col;
        if constexpr (OUTMODE == 0) {
          ((float*)Cp)[o] = v;
        } else if constexpr (OUTMODE == 1) {
          ((_Float16*)Cp)[o] = (_Float16)v;
        } else {
          ((float*)Cp)[o] = v;
          _Float16 h = (_Float16)v;
          Cs0[o] = h;
          Cs1[o] = (_Float16)((v - (float)h) * LO_SCALE);
        }
      }
}

// ---------------- weight transpose + split convert: W[K,N] -> T[N,K] f16 ----------------
template<int NS>
__global__ __launch_bounds__(256) void tconv(const float* __restrict__ Wsrc,
                                             _Float16* __restrict__ T0,
                                             _Float16* __restrict__ T1, int K, int N)
{
  __shared__ float t[32][33];
  const int kb = blockIdx.y * 32, nb = blockIdx.x * 32;
  const int tx = threadIdx.x & 31, ty = threadIdx.x >> 5;
#pragma unroll
  for (int i = 0; i < 32; i += 8)
    t[ty + i][tx] = Wsrc[(size_t)(kb + ty + i) * N + nb + tx];
  __syncthreads();
#pragma unroll
  for (int i = 0; i < 32; i += 8) {
    float v = t[tx][ty + i];
    size_t o = (size_t)(nb + ty + i) * K + kb + tx;
    _Float16 h = (_Float16)v;
    T0[o] = h;
    if constexpr (NS >= 2) T1[o] = (_Float16)((v - (float)h) * LO_SCALE);
  }
}

// ---------------- flat f32 -> f16 split2 (8 elems/thread) ----------------
__global__ __launch_bounds__(256) void cvt2(const float* __restrict__ in,
                                            _Float16* __restrict__ oh,
                                            _Float16* __restrict__ ol, int n)
{
  const int i = (blockIdx.x * 256 + threadIdx.x) * 8;
  if (i >= n) return;
  float4 va = *(const float4*)(in + i);
  float4 vb = *(const float4*)(in + i + 4);
  float f[8] = {va.x, va.y, va.z, va.w, vb.x, vb.y, vb.z, vb.w};
  f16x8 hv, lv;
#pragma unroll
  for (int e = 0; e < 8; e++) {
    _Float16 h = (_Float16)f[e];
    hv[e] = h;
    lv[e] = (_Float16)((f[e] - (float)h) * LO_SCALE);
  }
  *(f16x8*)(oh + i) = hv;
  *(f16x8*)(ol + i) = lv;
}

// ---------------- codebook: split convert + squared norms ----------------
__global__ __launch_bounds__(256) void cbconv(const float* __restrict__ cb,
                                              _Float16* __restrict__ ch,
                                              _Float16* __restrict__ cl,
                                              float* __restrict__ cn2)
{
  __shared__ float sb[256];
  const int r = blockIdx.x, t = threadIdx.x;
  const size_t o = (size_t)r * EMB + t;
  const float v = cb[o];
  _Float16 h = (_Float16)v;
  ch[o] = h;
  cl[o] = (_Float16)((v - (float)h) * LO_SCALE);
  float s = blk_reduce_sum(v * v, sb);
  if (t == 0) cn2[r] = s;
}

// ---------------- fused SiLU + LayerNorm -> f16 (split2 or plain) ----------------
template<int NCOL, int NS>
__global__ __launch_bounds__(256) void silu_ln(const float* __restrict__ in,
                                               const float* __restrict__ g,
                                               const float* __restrict__ bta,
                                               _Float16* __restrict__ o0,
                                               _Float16* __restrict__ o1)
{
  constexpr int PT = NCOL / 256;
  __shared__ float sb[256];
  const int b = blockIdx.x, t = threadIdx.x;
  const float* row = in + (size_t)b * NCOL;
  float v[PT];
  float s = 0.f;
#pragma unroll
  for (int i = 0; i < PT; i++) {
    float x = row[t + 256 * i];
    float sv = x / (1.f + expf(-x));
    v[i] = sv; s += sv;
  }
  s = blk_reduce_sum(s, sb);
  const float mu = s / (float)NCOL;
  float q = 0.f;
#pragma unroll
  for (int i = 0; i < PT; i++) { float d = v[i] - mu; q += d * d; }
  q = blk_reduce_sum(q, sb);
  const float inv = 1.f / sqrtf(q / (float)NCOL + 1e-5f);
#pragma unroll
  for (int i = 0; i < PT; i++) {
    const int c = t + 256 * i;
    const float y = (v[i] - mu) * inv * g[c] + bta[c];
    const size_t o = (size_t)b * NCOL + c;
    _Float16 h = (_Float16)y;
    o0[o] = h;
    if constexpr (NS >= 2) o1[o] = (_Float16)((y - (float)h) * LO_SCALE);
  }
}

// ---------------- fused gumbel-max sampler + rotation-trick update ----------------
__global__ __launch_bounds__(256) void sample_update(
    const float* __restrict__ S, const float* __restrict__ cn2l,
    const float* __restrict__ cbf,
    float* __restrict__ res, float* __restrict__ esum,
    float* __restrict__ qrow, float* __restrict__ outEn,
    _Float16* __restrict__ r0, _Float16* __restrict__ r1,
    _Float16* __restrict__ esumb, int* __restrict__ ids,
    uint32_t* __restrict__ packed,
    uint32_t k0, uint32_t k1, int layer)
{
  __shared__ float sv[256];
  __shared__ int   si[256];
  const int b = blockIdx.x, t = threadIdx.x;
  const float* Srow = S + (size_t)b * KCB;

  // --- sampler phase (exact jax.random.categorical via gumbel-max) ---
  float best = -INFINITY; int bestj = 0x7fffffff;
#pragma unroll
  for (int jj = 0; jj < 4; ++jj) {
    const int j = t + jj * 256;
    const uint32_t idx = (uint32_t)(b * KCB + j);
    uint32_t o0, o1;
    tf2x32(k0, k1, 0u, idx, o0, o1);
    uint32_t bits = o0 ^ o1;
    float f = __uint_as_float((bits >> 9) | 0x3f800000u) - 1.0f;
    float u = fmaxf(f, 1.17549435e-38f);
    float gmb = -__logf(-__logf(u));
    float logit = (2.0f * Srow[j] - cn2l[j]) / 1.25f;
    float val = gmb + logit;
    if (val > best || (val == best && j < bestj)) { best = val; bestj = j; }
  }
  sv[t] = best; si[t] = bestj; __syncthreads();
  for (int s = 128; s > 0; s >>= 1) {
    if (t < s) {
      float v2 = sv[t + s]; int j2 = si[t + s];
      if (v2 > sv[t] || (v2 == sv[t] && j2 < si[t])) { sv[t] = v2; si[t] = j2; }
    }
    __syncthreads();
  }
  const int id = si[0];
  if (t == 0) {
    ids[b * NLAYER + layer] = id;
    if (layer == NLAYER - 1)
      packed[b] = (uint32_t)ids[b * NLAYER] | ((uint32_t)ids[b * NLAYER + 1] << 10)
                | ((uint32_t)id << 20);
  }
  __syncthreads();

  // --- rotation-trick update phase ---
  const size_t idx = (size_t)b * EMB + t;
  const float r = res[idx];
  const float e_ = cbf[(size_t)id * EMB + t];

  const float rn2 = blk_reduce_sum(r * r, sv);
  const float en2 = blk_reduce_sum(e_ * e_, sv);
  const float rn = sqrtf(rn2), en = sqrtf(en2);
  const float u = r / (rn + 1e-8f);
  const float q = e_ / (en + 1e-8f);
  const float sm = u + q;
  const float sn2 = blk_reduce_sum(sm * sm, sv);
  const float w = sm / fmaxf(sqrtf(sn2), 1e-6f);
  const float rw = blk_reduce_sum(r * w, sv);
  const float ru = blk_reduce_sum(r * u, sv);
  const float e = r - 2.f * rw * w + 2.f * ru * q;
  const float eo2 = blk_reduce_sum(e * e, sv);
  const float dq = r - e_;
  const float ql = blk_reduce_sum(dq * dq, sv);

  if (t == 0) {
    outEn[b * NLAYER + layer] = sqrtf(eo2);
    if (layer == 0) qrow[b] = 1.25f * ql; else qrow[b] += 1.25f * ql;
  }
  const float nr = r - e;
  res[idx] = nr;
  {
    _Float16 h = (_Float16)nr;
    r0[idx] = h;
    r1[idx] = (_Float16)((nr - (float)h) * LO_SCALE);
  }
  float ns = (layer == 0) ? e : esum[idx] + e;
  esum[idx] = ns;
  if (layer == NLAYER - 1) esumb[idx] = (_Float16)ns;
}

// ---------------- final l2norm + per-row recon (y in f16) ----------------
__global__ __launch_bounds__(256) void l2norm_recon(const _Float16* __restrict__ y,
                                                    const float* __restrict__ x,
                                                    float* __restrict__ recon)
{
  __shared__ float sb[256];
  const int b = blockIdx.x, t = threadIdx.x;
  const _Float16* yr = y + (size_t)b * INDIM;
  const float* xr = x + (size_t)b * INDIM;
  f16x8 v = *(const f16x8*)&yr[t * 8];
  float vy[8];
  float ss = 0.f;
#pragma unroll
  for (int i = 0; i < 8; i++) { vy[i] = (float)v[i]; ss += vy[i] * vy[i]; }
  ss = blk_reduce_sum(ss, sb);
  const float inv = 1.f / fmaxf(sqrtf(ss), 1e-12f);
  float4 xa = *(const float4*)&xr[t * 8];
  float4 xb = *(const float4*)&xr[t * 8 + 4];
  float xf[8] = {xa.x, xa.y, xa.z, xa.w, xb.x, xb.y, xb.z, xb.w};
  float acc = 0.f;
#pragma unroll
  for (int i = 0; i < 8; i++) {
    float d = vy[i] * inv - xf[i];
    acc += d * d;
  }
  acc = blk_reduce_sum(acc, sb);
  if (t == 0) recon[b] = acc;
}

// ---------------- distinct count (hash set): p_unique numerator ----------------
// # rows with no later duplicate == # distinct values (each distinct value's
// last occurrence has no later duplicate; all other occurrences do).
__global__ __launch_bounds__(256) void hash_init(uint32_t* __restrict__ table,
                                                 int* __restrict__ cnt)
{
  const int i = blockIdx.x * 256 + threadIdx.x;
  if (i < HASHN) table[i] = 0xFFFFFFFFu;
  if (i == 0) *cnt = 0;
}

__global__ __launch_bounds__(256) void distinct_count(const uint32_t* __restrict__ packed,
                                                      uint32_t* __restrict__ table,
                                                      int* __restrict__ cnt)
{
  const int i = blockIdx.x * 256 + threadIdx.x;
  if (i >= NB) return;
  const uint32_t v = packed[i];
  uint32_t h = (v * 2654435761u) & (HASHN - 1);
  while (true) {
    uint32_t old = atomicCAS(&table[h], 0xFFFFFFFFu, v);
    if (old == 0xFFFFFFFFu) { atomicAdd(cnt, 1); break; }
    if (old == v) break;
    h = (h + 1) & (HASHN - 1);
  }
}

// ---------------- finalize scalars ----------------
__global__ __launch_bounds__(256) void finalize(const float* __restrict__ recon,
                                                const float* __restrict__ qrow,
                                                const int* __restrict__ dcnt,
                                                float* __restrict__ out)
{
  __shared__ double sd[256];
  const int t = threadIdx.x;
  double aR = 0.0, aQ = 0.0;
  for (int i = t; i < NB; i += 256) { aR += (double)recon[i]; aQ += (double)qrow[i]; }
  sd[t] = aR; __syncthreads();
  for (int s = 128; s > 0; s >>= 1) { if (t < s) sd[t] += sd[t + s]; __syncthreads(); }
  const double sumR = sd[0]; __syncthreads();
  sd[t] = aQ; __syncthreads();
  for (int s = 128; s > 0; s >>= 1) { if (t < s) sd[t] += sd[t + s]; __syncthreads(); }
  const double sumQ = sd[0]; __syncthreads();
  if (t == 0) {
    const float rm = (float)(sumR / (double)NB);
    const float ql = (float)sumQ;
    out[0] = rm + ql;
    out[1] = rm;
    out[2] = ql;
    out[3 + NB * NLAYER] = (float)(*dcnt) / (float)NB;
  }
}

// ---------------- host launch ----------------
extern "C" void kernel_launch(void* const* d_in, const int* in_sizes, int n_in,
                              void* d_out, int out_size, void* d_ws, size_t ws_size,
                              hipStream_t stream)
{
  const float* x      = (const float*)d_in[0];
  const float* enc_w1 = (const float*)d_in[1];
  const float* enc_g1 = (const float*)d_in[2];
  const float* enc_b1 = (const float*)d_in[3];
  const float* enc_w2 = (const float*)d_in[4];
  const float* enc_g2 = (const float*)d_in[5];
  const float* enc_b2 = (const float*)d_in[6];
  const float* enc_w3 = (const float*)d_in[7];
  const float* dec_w1 = (const float*)d_in[8];
  const float* dec_g1 = (const float*)d_in[9];
  const float* dec_b1 = (const float*)d_in[10];
  const float* dec_w2 = (const float*)d_in[11];
  const float* dec_g2 = (const float*)d_in[12];
  const float* dec_b2 = (const float*)d_in[13];
  const float* dec_w3 = (const float*)d_in[14];
  const float* codebooks = (const float*)d_in[15];
  float* out = (float*)d_out;

  char* W = (char*)d_ws;
  // region [0,32MB): xh -> h1n0/h1n1 -> h2n0/h2n1 + res0/res1 -> d1n/d2n
  _Float16* xh   = (_Float16*)(W + 0);          // 32MB, dies after enc1
  _Float16* h1n0 = (_Float16*)(W + 0);          // 16MB
  _Float16* h1n1 = (_Float16*)(W + 16777216);   // 16MB
  _Float16* h2n0 = (_Float16*)(W + 0);          // 8MB
  _Float16* h2n1 = (_Float16*)(W + 8388608);    // 8MB
  _Float16* res0 = (_Float16*)(W + 16777216);   // 4MB  (lives through quant loop)
  _Float16* res1 = (_Float16*)(W + 20971520);   // 4MB
  _Float16* d1n  = (_Float16*)(W + 0);          // 8MB (decoder phase)
  _Float16* d2n  = (_Float16*)(W + 25165824);   // 16MB [24,40)
  // region [32,64MB): xl -> h2 f32 / d1 f32 ; res32/esum32 at top
  _Float16* xl    = (_Float16*)(W + 33554432);  // 32MB, dies after enc1
  float*    h2    = (float*)  (W + 33554432);   // 16MB
  float*    d1    = (float*)  (W + 33554432);   // 16MB
  float*    res32 = (float*)  (W + 50331648);   // 8MB
  float*    esum32= (float*)  (W + 58720256);   // 8MB
  // region [64,96MB): h1 f32 -> S -> d2 f32 -> y f16
  float*    h1 = (float*)    (W + 67108864);    // 32MB
  float*    S  = (float*)    (W + 67108864);    // 32MB
  float*    d2 = (float*)    (W + 67108864);    // 32MB
  _Float16* yb = (_Float16*) (W + 67108864);    // 32MB
  // weights region [96MB+)
  _Float16* w1t0 = (_Float16*)(W + 100663296);  // 4MB
  _Float16* w1t1 = (_Float16*)(W + 104857600);  // 4MB
  _Float16* w2t0 = (_Float16*)(W + 109051904);  // 1MB
  _Float16* w2t1 = (_Float16*)(W + 110100480);  // 1MB
  _Float16* w3t0 = (_Float16*)(W + 111149056);  // 256KB
  _Float16* w3t1 = (_Float16*)(W + 111411200);  // 256KB
  _Float16* dw1t = (_Float16*)(W + 111673344);  // 256KB
  _Float16* dw2t = (_Float16*)(W + 111935488);  // 1MB
  _Float16* dw3t = (_Float16*)(W + 112984064);  // 4MB
  _Float16* cbh  = (_Float16*)(W + 117178368);  // 1.5MB
  _Float16* cbl  = (_Float16*)(W + 118751232);  // 1.5MB
  _Float16* esumb= (_Float16*)(W + 120324096);  // 4MB
  float* cn2   = (float*)(W + 124518400);
  float* recon = (float*)(W + 124534784);
  float* qrow  = (float*)(W + 124567552);
  int*   ids   = (int*)  (W + 124600320);
  uint32_t* packed = (uint32_t*)(W + 124698624);
  uint32_t* htab   = (uint32_t*)(W + 124731392); // 64KB
  int*      dcnt   = (int*)     (W + 124796928);

  // PRNG keys: jax.random.split(jax.random.key(42), 3), partitionable scheme
  uint32_t key0[NLAYER], key1[NLAYER];
  for (int l = 0; l < NLAYER; l++) tf2x32(0u, 42u, 0u, (uint32_t)l, key0[l], key1[l]);

  dim3 blk(256);
  // ---- weight / input / codebook conversion ----
  tconv<2><<<dim3(H1N/32, INDIM/32), blk, 0, stream>>>(enc_w1, w1t0, w1t1, INDIM, H1N);
  tconv<2><<<dim3(H2N/32, H1N/32), blk, 0, stream>>>(enc_w2, w2t0, w2t1, H1N, H2N);
  tconv<2><<<dim3(EMB/32, H2N/32), blk, 0, stream>>>(enc_w3, w3t0, w3t1, H2N, EMB);
  tconv<1><<<dim3(H2N/32, EMB/32), blk, 0, stream>>>(dec_w1, dw1t, nullptr, EMB, H2N);
  tconv<1><<<dim3(H1N/32, H2N/32), blk, 0, stream>>>(dec_w2, dw2t, nullptr, H2N, H1N);
  tconv<1><<<dim3(INDIM/32, H1N/32), blk, 0, stream>>>(dec_w3, dw3t, nullptr, H1N, INDIM);
  cvt2<<<(NB*INDIM)/2048, blk, 0, stream>>>(x, xh, xl, NB*INDIM);
  cbconv<<<NLAYER*KCB, blk, 0, stream>>>(codebooks, cbh, cbl, cn2);
  hash_init<<<HASHN/256, blk, 0, stream>>>(htab, dcnt);

  // ---- encoder (f16 split2, fp32-class) ----
  mgemm<2,0><<<dim3(H1N/128, NB/128), blk, 0, stream>>>(xh, xl, w1t0, w1t1,
      h1, nullptr, nullptr, NB, H1N, INDIM);
  silu_ln<H1N,2><<<NB, blk, 0, stream>>>(h1, enc_g1, enc_b1, h1n0, h1n1);
  mgemm<2,0><<<dim3(H2N/128, NB/128), blk, 0, stream>>>(h1n0, h1n1, w2t0, w2t1,
      h2, nullptr, nullptr, NB, H2N, H1N);
  silu_ln<H2N,2><<<NB, blk, 0, stream>>>(h2, enc_g2, enc_b2, h2n0, h2n1);
  mgemm<2,2><<<dim3(EMB/128, NB/128), blk, 0, stream>>>(h2n0, h2n1, w3t0, w3t1,
      res32, res0, res1, NB, EMB, H2N);

  // ---- quantization ----
  for (int l = 0; l < NLAYER; l++) {
    const float* cbfl = codebooks + (size_t)l * KCB * EMB;
    const size_t co = (size_t)l * KCB * EMB;
    mgemm<2,0><<<dim3(KCB/128, NB/128), blk, 0, stream>>>(res0, res1,
        cbh + co, cbl + co, S, nullptr, nullptr, NB, KCB, EMB);
    sample_update<<<NB, blk, 0, stream>>>(S, cn2 + l * KCB, cbfl,
        res32, esum32, qrow, out + 3, res0, res1, esumb, ids, packed,
        key0[l], key1[l], l);
  }

  // ---- decoder (f16 single product) ----
  mgemm<1,0><<<dim3(H2N/128, NB/128), blk, 0, stream>>>(esumb, nullptr, dw1t, nullptr,
      d1, nullptr, nullptr, NB, H2N, EMB);
  silu_ln<H2N,1><<<NB, blk, 0, stream>>>(d1, dec_g1, dec_b1, d1n, nullptr);
  mgemm<1,0><<<dim3(H1N/128, NB/128), blk, 0, stream>>>(d1n, nullptr, dw2t, nullptr,
      d2, nullptr, nullptr, NB, H1N, H2N);
  silu_ln<H1N,1><<<NB, blk, 0, stream>>>(d2, dec_g2, dec_b2, d2n, nullptr);
  mgemm<1,1><<<dim3(INDIM/128, NB/128), blk, 0, stream>>>(d2n, nullptr, dw3t, nullptr,
      yb, nullptr, nullptr, NB, INDIM, H1N);
  l2norm_recon<<<NB, blk, 0, stream>>>(yb, x, recon);

  // ---- p_unique + scalars ----
  distinct_count<<<NB/256, blk, 0, stream>>>(packed, htab, dcnt);
  finalize<<<1, blk, 0, stream>>>(recon, qrow, dcnt, out);
}

// Round 5
// 687.810 us; speedup vs baseline: 2.7841x; 1.0102x over previous
//
#include <hip/hip_runtime.h>
#include <hip/hip_bf16.h>
#include <stdint.h>
#include <math.h>

// ---------------- problem constants ----------------
#define NB    8192
#define INDIM 2048
#define EMB   256
#define H1N   1024
#define H2N   512
#define KCB   1024
#define NLAYER 3
#define HASHN 16384

typedef _Float16 f16x8 __attribute__((ext_vector_type(8)));
typedef float    f32x4 __attribute__((ext_vector_type(4)));

#define LO_SCALE 1024.0f
#define LO_INV   (1.0f / 1024.0f)

#define GLD16(g, p) __builtin_amdgcn_global_load_lds( \
    (const __attribute__((address_space(1))) void*)(g), \
    (__attribute__((address_space(3))) void*)(p), 16, 0, 0)

// ---------------- threefry2x32 (20 rounds) ----------------
__host__ __device__ inline void tf2x32(uint32_t k0, uint32_t k1, uint32_t x0, uint32_t x1,
                                       uint32_t& o0, uint32_t& o1)
{
  const uint32_t ks2 = 0x1BD11BDAu ^ k0 ^ k1;
  uint32_t a = x0 + k0, b = x1 + k1;
#define TF_RND(r) { a += b; b = (b << (r)) | (b >> (32 - (r))); b ^= a; }
  TF_RND(13) TF_RND(15) TF_RND(26) TF_RND(6)
  a += k1; b += ks2 + 1u;
  TF_RND(17) TF_RND(29) TF_RND(16) TF_RND(24)
  a += ks2; b += k0 + 2u;
  TF_RND(13) TF_RND(15) TF_RND(26) TF_RND(6)
  a += k0; b += k1 + 3u;
  TF_RND(17) TF_RND(29) TF_RND(16) TF_RND(24)
  a += k1; b += ks2 + 4u;
  TF_RND(13) TF_RND(15) TF_RND(26) TF_RND(6)
  a += ks2; b += k0 + 5u;
#undef TF_RND
  o0 = a; o1 = b;
}

__device__ inline float blk_reduce_sum(float v, float* sbuf)
{
  const int t = threadIdx.x;
  sbuf[t] = v; __syncthreads();
  for (int s = 128; s > 0; s >>= 1) {
    if (t < s) sbuf[t] += sbuf[t + s];
    __syncthreads();
  }
  float r = sbuf[0];
  __syncthreads();
  return r;
}

// =================== MFMA GEMM (fp16, split-2, double-buffered) ===================
// C[M,N] = A[M,K] * B[N,K]^T.  A/B given as f16 hi (+ lo*1024 when NS==2).
// NS==2: acc0 += hi*hi; acc1 += hi*lo' + lo'*hi; C = acc0 + acc1/1024.
// OUTMODE: 0 = f32; 1 = f16 hi only; 2 = f32 + f16 split2 (Cs0/Cs1);
//          3 = no C write: fused gumbel-max partial argmax (dist GEMM).
template<int NS, int OUTMODE>
__global__ __launch_bounds__(256) void mgemm(
    const _Float16* __restrict__ A0, const _Float16* __restrict__ A1,
    const _Float16* __restrict__ B0, const _Float16* __restrict__ B1,
    void* __restrict__ Cp, _Float16* __restrict__ Cs0, _Float16* __restrict__ Cs1,
    float* __restrict__ pval, int* __restrict__ pidx, const float* __restrict__ cn2l,
    uint32_t gk0, uint32_t gk1,
    int M, int N, int K)
{
  constexpr int ABYTES = NS * 8192;           // per-buffer A (or B) region
  __shared__ __align__(16) char sm[4 * ABYTES];  // 2 buffers x (A+B)

  // XCD-aware bijective swizzle (all grids here have nwg % 8 == 0)
  const int nwg = gridDim.x * gridDim.y;
  const int bid0 = blockIdx.y * gridDim.x + blockIdx.x;
  const int cpx = nwg >> 3;
  const int swz = (bid0 & 7) * cpx + (bid0 >> 3);
  const int bx = swz % gridDim.x, by = swz / gridDim.x;

  const int tid = threadIdx.x;
  const int w = tid >> 6, l = tid & 63;
  const int wm = w >> 1, wn = w & 1;
  const size_t brow = (size_t)by * 128;
  const size_t bcol = (size_t)bx * 128;

  // staging (pre-swizzled global source; linear LDS dest)
  const int brow16 = w * 16 + (l >> 2);
  const int bcol16 = ((l & 3) ^ ((l >> 3) & 3)) * 8;

  const _Float16* gA0 = A0 + (brow + brow16) * (size_t)K + bcol16;
  const _Float16* gA1 = (NS >= 2) ? (A1 + (brow + brow16) * (size_t)K + bcol16) : nullptr;
  const _Float16* gB0 = B0 + (bcol + brow16) * (size_t)K + bcol16;
  const _Float16* gB1 = (NS >= 2) ? (B1 + (bcol + brow16) * (size_t)K + bcol16) : nullptr;

  auto STAGE = [&](int buf, int kk) {
    char* bA = sm + buf * 2 * ABYTES;
    char* bB = bA + ABYTES;
#pragma unroll
    for (int i = 0; i < 2; i++) {
      GLD16(gA0 + (size_t)(i * 64) * K + kk, bA + i * 4096 + w * 1024);
      if constexpr (NS >= 2) GLD16(gA1 + (size_t)(i * 64) * K + kk, bA + 8192 + i * 4096 + w * 1024);
      GLD16(gB0 + (size_t)(i * 64) * K + kk, bB + i * 4096 + w * 1024);
      if constexpr (NS >= 2) GLD16(gB1 + (size_t)(i * 64) * K + kk, bB + 8192 + i * 4096 + w * 1024);
    }
  };

  f32x4 acc0[4][4], acc1[4][4];
#pragma unroll
  for (int i = 0; i < 4; i++)
#pragma unroll
    for (int j = 0; j < 4; j++) {
      acc0[i][j] = (f32x4){0.f, 0.f, 0.f, 0.f};
      if constexpr (NS >= 2) acc1[i][j] = (f32x4){0.f, 0.f, 0.f, 0.f};
    }

  const int srow = l & 15;
  const int ksel = l >> 4;
  const int sel2 = (srow >> 1) & 3;
  const int fslot16 = (ksel ^ sel2) * 16;

  STAGE(0, 0);
  __syncthreads();   // implicit vmcnt(0) drain of prologue stage
  int cur = 0;

  for (int k0 = 0; k0 < K; k0 += 32) {
    if (k0 + 32 < K) STAGE(cur ^ 1, k0 + 32);   // prefetch next tile (in flight over MFMAs)

    const char* smA = sm + cur * 2 * ABYTES;
    const char* smB = smA + ABYTES;

    f16x8 ah[4], al[4];
#pragma unroll
    for (int i = 0; i < 4; i++) {
      const int rb = (wm * 64 + i * 16 + srow) * 64 + fslot16;
      ah[i] = *(const f16x8*)(smA + rb);
      if constexpr (NS >= 2) al[i] = *(const f16x8*)(smA + 8192 + rb);
    }

#pragma unroll
    for (int j = 0; j < 4; j++) {
      const int rb = (wn * 64 + j * 16 + srow) * 64 + fslot16;
      f16x8 bh = *(const f16x8*)(smB + rb);
      f16x8 bl{};
      if constexpr (NS >= 2) bl = *(const f16x8*)(smB + 8192 + rb);
#pragma unroll
      for (int i = 0; i < 4; i++) {
        acc0[i][j] = __builtin_amdgcn_mfma_f32_16x16x32_f16(ah[i], bh, acc0[i][j], 0, 0, 0);
        if constexpr (NS >= 2) {
          acc1[i][j] = __builtin_amdgcn_mfma_f32_16x16x32_f16(ah[i], bl, acc1[i][j], 0, 0, 0);
          acc1[i][j] = __builtin_amdgcn_mfma_f32_16x16x32_f16(al[i], bh, acc1[i][j], 0, 0, 0);
        }
      }
    }
    __syncthreads();  // drains prefetch vmcnt + protects buffer reuse
    cur ^= 1;
  }

  if constexpr (OUTMODE == 3) {
    // ---- fused gumbel-max partial argmax over this block's 128 cols ----
    const int rowb = (int)brow + wm * 64 + (l >> 4) * 4;
    const int colb = (int)bcol + wn * 64 + (l & 15);
#pragma unroll
    for (int i = 0; i < 4; i++)
#pragma unroll
      for (int r = 0; r < 4; r++) {
        const int grow = rowb + i * 16 + r;
        float bestv = -INFINITY; int bestj = 0x7fffffff;
#pragma unroll
        for (int j = 0; j < 4; j++) {
          float v = acc0[i][j][r];
          if constexpr (NS >= 2) v += acc1[i][j][r] * LO_INV;
          const int gcol = colb + j * 16;
          const uint32_t idx = (uint32_t)(grow * KCB + gcol);
          uint32_t o0, o1;
          tf2x32(gk0, gk1, 0u, idx, o0, o1);
          const uint32_t bits = o0 ^ o1;
          float f = __uint_as_float((bits >> 9) | 0x3f800000u) - 1.0f;
          float u = fmaxf(f, 1.17549435e-38f);
          float gmb = -__logf(-__logf(u));
          float val = gmb + (2.0f * v - cn2l[gcol]) / 1.25f;
          if (val > bestv || (val == bestv && gcol < bestj)) { bestv = val; bestj = gcol; }
        }
        // reduce across the 16 lanes sharing this row
#pragma unroll
        for (int m = 1; m < 16; m <<= 1) {
          float ov = __shfl_xor(bestv, m);
          int oj = __shfl_xor(bestj, m);
          if (ov > bestv || (ov == bestv && oj < bestj)) { bestv = ov; bestj = oj; }
        }
        if ((l & 15) == 0) {
          const int slot = bx * 2 + wn;            // 16 slots (gridDim.x==8)
          pval[(size_t)grow * 16 + slot] = bestv;
          pidx[(size_t)grow * 16 + slot] = bestj;
        }
      }
  } else {
    // ---- epilogue: C/D layout col=lane&15, row=(lane>>4)*4+r ----
    const int crow0 = wm * 64 + (l >> 4) * 4;
    const int ccol0 = wn * 64 + (l & 15);
#pragma unroll
    for (int i = 0; i < 4; i++)
#pragma unroll
      for (int j = 0; j < 4; j++)
#pragma unroll
        for (int r = 0; r < 4; r++) {
          float v = acc0[i][j][r];
          if constexpr (NS >= 2) v += acc1[i][j][r] * LO_INV;
          const size_t row = brow + crow0 + i * 16 + r;
          const size_t col = bcol + ccol0 + j * 16;
          const size_t o = row * N + col;
          if constexpr (OUTMODE == 0) {
            ((float*)Cp)[o] = v;
          } else if constexpr (OUTMODE == 1) {
            ((_Float16*)Cp)[o] = (_Float16)v;
          } else {
            ((float*)Cp)[o] = v;
            _Float16 h = (_Float16)v;
            Cs0[o] = h;
            Cs1[o] = (_Float16)((v - (float)h) * LO_SCALE);
          }
        }
  }
}

// ---------------- all weight transposes in ONE launch ----------------
struct TJobs {
  const float* w[6];
  _Float16* t0[6];
  _Float16* t1[6];   // null => NS1
  int K[6], N[6];
  int off[7];
};

__global__ __launch_bounds__(256) void tconv_all(TJobs J)
{
  __shared__ float t[32][33];
  const int b = blockIdx.x;
  int j = 0;
  while (b >= J.off[j + 1]) j++;
  const int lb = b - J.off[j];
  const int K = J.K[j], N = J.N[j];
  const int nbx = N / 32;
  const int nb = (lb % nbx) * 32, kb = (lb / nbx) * 32;
  const float* Wsrc = J.w[j];
  _Float16* T0 = J.t0[j];
  _Float16* T1 = J.t1[j];

  const int tx = threadIdx.x & 31, ty = threadIdx.x >> 5;
#pragma unroll
  for (int i = 0; i < 32; i += 8)
    t[ty + i][tx] = Wsrc[(size_t)(kb + ty + i) * N + nb + tx];
  __syncthreads();
#pragma unroll
  for (int i = 0; i < 32; i += 8) {
    float v = t[tx][ty + i];
    size_t o = (size_t)(nb + ty + i) * K + kb + tx;
    _Float16 h = (_Float16)v;
    T0[o] = h;
    if (T1) T1[o] = (_Float16)((v - (float)h) * LO_SCALE);
  }
}

// ---------------- flat f32 -> f16 split2 (8 elems/thread) ----------------
__global__ __launch_bounds__(256) void cvt2(const float* __restrict__ in,
                                            _Float16* __restrict__ oh,
                                            _Float16* __restrict__ ol, int n)
{
  const int i = (blockIdx.x * 256 + threadIdx.x) * 8;
  if (i >= n) return;
  float4 va = *(const float4*)(in + i);
  float4 vb = *(const float4*)(in + i + 4);
  float f[8] = {va.x, va.y, va.z, va.w, vb.x, vb.y, vb.z, vb.w};
  f16x8 hv, lv;
#pragma unroll
  for (int e = 0; e < 8; e++) {
    _Float16 h = (_Float16)f[e];
    hv[e] = h;
    lv[e] = (_Float16)((f[e] - (float)h) * LO_SCALE);
  }
  *(f16x8*)(oh + i) = hv;
  *(f16x8*)(ol + i) = lv;
}

// ---------------- codebook: split convert + squared norms ----------------
__global__ __launch_bounds__(256) void cbconv(const float* __restrict__ cb,
                                              _Float16* __restrict__ ch,
                                              _Float16* __restrict__ cl,
                                              float* __restrict__ cn2)
{
  __shared__ float sb[256];
  const int r = blockIdx.x, t = threadIdx.x;
  const size_t o = (size_t)r * EMB + t;
  const float v = cb[o];
  _Float16 h = (_Float16)v;
  ch[o] = h;
  cl[o] = (_Float16)((v - (float)h) * LO_SCALE);
  float s = blk_reduce_sum(v * v, sb);
  if (t == 0) cn2[r] = s;
}

// ---------------- fused SiLU + LayerNorm -> f16 (split2 or plain) ----------------
template<int NCOL, int NS>
__global__ __launch_bounds__(256) void silu_ln(const float* __restrict__ in,
                                               const float* __restrict__ g,
                                               const float* __restrict__ bta,
                                               _Float16* __restrict__ o0,
                                               _Float16* __restrict__ o1)
{
  constexpr int PT = NCOL / 256;
  __shared__ float sb[256];
  const int b = blockIdx.x, t = threadIdx.x;
  const float* row = in + (size_t)b * NCOL;
  float v[PT];
  float s = 0.f;
#pragma unroll
  for (int i = 0; i < PT; i++) {
    float x = row[t + 256 * i];
    float sv = x / (1.f + expf(-x));
    v[i] = sv; s += sv;
  }
  s = blk_reduce_sum(s, sb);
  const float mu = s / (float)NCOL;
  float q = 0.f;
#pragma unroll
  for (int i = 0; i < PT; i++) { float d = v[i] - mu; q += d * d; }
  q = blk_reduce_sum(q, sb);
  const float inv = 1.f / sqrtf(q / (float)NCOL + 1e-5f);
#pragma unroll
  for (int i = 0; i < PT; i++) {
    const int c = t + 256 * i;
    const float y = (v[i] - mu) * inv * g[c] + bta[c];
    const size_t o = (size_t)b * NCOL + c;
    _Float16 h = (_Float16)y;
    o0[o] = h;
    if constexpr (NS >= 2) o1[o] = (_Float16)((y - (float)h) * LO_SCALE);
  }
}

// ---------------- slim sampler (combine 16 partials) + rotation-trick update ----------------
__global__ __launch_bounds__(256) void sample_update(
    const float* __restrict__ pval, const int* __restrict__ pidx,
    const float* __restrict__ cbf,
    float* __restrict__ res, float* __restrict__ esum,
    float* __restrict__ qrow, float* __restrict__ outEn,
    _Float16* __restrict__ r0, _Float16* __restrict__ r1,
    _Float16* __restrict__ esumb, int* __restrict__ ids,
    uint32_t* __restrict__ packed, int layer)
{
  __shared__ float sv[256];
  __shared__ int   si[256];
  const int b = blockIdx.x, t = threadIdx.x;

  float best = -INFINITY; int bestj = 0x7fffffff;
  if (t < 16) { best = pval[(size_t)b * 16 + t]; bestj = pidx[(size_t)b * 16 + t]; }
  sv[t] = best; si[t] = bestj; __syncthreads();
  for (int s = 128; s > 0; s >>= 1) {
    if (t < s) {
      float v2 = sv[t + s]; int j2 = si[t + s];
      if (v2 > sv[t] || (v2 == sv[t] && j2 < si[t])) { sv[t] = v2; si[t] = j2; }
    }
    __syncthreads();
  }
  const int id = si[0];
  if (t == 0) {
    ids[b * NLAYER + layer] = id;
    if (layer == NLAYER - 1)
      packed[b] = (uint32_t)ids[b * NLAYER] | ((uint32_t)ids[b * NLAYER + 1] << 10)
                | ((uint32_t)id << 20);
  }
  __syncthreads();

  // --- rotation-trick update phase ---
  const size_t idx = (size_t)b * EMB + t;
  const float r = res[idx];
  const float e_ = cbf[(size_t)id * EMB + t];

  const float rn2 = blk_reduce_sum(r * r, sv);
  const float en2 = blk_reduce_sum(e_ * e_, sv);
  const float rn = sqrtf(rn2), en = sqrtf(en2);
  const float u = r / (rn + 1e-8f);
  const float q = e_ / (en + 1e-8f);
  const float sm = u + q;
  const float sn2 = blk_reduce_sum(sm * sm, sv);
  const float w = sm / fmaxf(sqrtf(sn2), 1e-6f);
  const float rw = blk_reduce_sum(r * w, sv);
  const float ru = blk_reduce_sum(r * u, sv);
  const float e = r - 2.f * rw * w + 2.f * ru * q;
  const float eo2 = blk_reduce_sum(e * e, sv);
  const float dq = r - e_;
  const float ql = blk_reduce_sum(dq * dq, sv);

  if (t == 0) {
    outEn[b * NLAYER + layer] = sqrtf(eo2);
    if (layer == 0) qrow[b] = 1.25f * ql; else qrow[b] += 1.25f * ql;
  }
  const float nr = r - e;
  res[idx] = nr;
  {
    _Float16 h = (_Float16)nr;
    r0[idx] = h;
    r1[idx] = (_Float16)((nr - (float)h) * LO_SCALE);
  }
  float ns = (layer == 0) ? e : esum[idx] + e;
  esum[idx] = ns;
  if (layer == NLAYER - 1) esumb[idx] = (_Float16)ns;
}

// ---------------- final l2norm + per-row recon (y in f16) ----------------
__global__ __launch_bounds__(256) void l2norm_recon(const _Float16* __restrict__ y,
                                                    const float* __restrict__ x,
                                                    float* __restrict__ recon)
{
  __shared__ float sb[256];
  const int b = blockIdx.x, t = threadIdx.x;
  const _Float16* yr = y + (size_t)b * INDIM;
  const float* xr = x + (size_t)b * INDIM;
  f16x8 v = *(const f16x8*)&yr[t * 8];
  float vy[8];
  float ss = 0.f;
#pragma unroll
  for (int i = 0; i < 8; i++) { vy[i] = (float)v[i]; ss += vy[i] * vy[i]; }
  ss = blk_reduce_sum(ss, sb);
  const float inv = 1.f / fmaxf(sqrtf(ss), 1e-12f);
  float4 xa = *(const float4*)&xr[t * 8];
  float4 xb = *(const float4*)&xr[t * 8 + 4];
  float xf[8] = {xa.x, xa.y, xa.z, xa.w, xb.x, xb.y, xb.z, xb.w};
  float acc = 0.f;
#pragma unroll
  for (int i = 0; i < 8; i++) {
    float d = vy[i] * inv - xf[i];
    acc += d * d;
  }
  acc = blk_reduce_sum(acc, sb);
  if (t == 0) recon[b] = acc;
}

// ---------------- distinct count (hash set): p_unique numerator ----------------
__global__ __launch_bounds__(256) void hash_init(uint32_t* __restrict__ table,
                                                 int* __restrict__ cnt)
{
  const int i = blockIdx.x * 256 + threadIdx.x;
  if (i < HASHN) table[i] = 0xFFFFFFFFu;
  if (i == 0) *cnt = 0;
}

__global__ __launch_bounds__(256) void distinct_count(const uint32_t* __restrict__ packed,
                                                      uint32_t* __restrict__ table,
                                                      int* __restrict__ cnt)
{
  const int i = blockIdx.x * 256 + threadIdx.x;
  if (i >= NB) return;
  const uint32_t v = packed[i];
  uint32_t h = (v * 2654435761u) & (HASHN - 1);
  while (true) {
    uint32_t old = atomicCAS(&table[h], 0xFFFFFFFFu, v);
    if (old == 0xFFFFFFFFu) { atomicAdd(cnt, 1); break; }
    if (old == v) break;
    h = (h + 1) & (HASHN - 1);
  }
}

// ---------------- finalize scalars ----------------
__global__ __launch_bounds__(256) void finalize(const float* __restrict__ recon,
                                                const float* __restrict__ qrow,
                                                const int* __restrict__ dcnt,
                                                float* __restrict__ out)
{
  __shared__ double sd[256];
  const int t = threadIdx.x;
  double aR = 0.0, aQ = 0.0;
  for (int i = t; i < NB; i += 256) { aR += (double)recon[i]; aQ += (double)qrow[i]; }
  sd[t] = aR; __syncthreads();
  for (int s = 128; s > 0; s >>= 1) { if (t < s) sd[t] += sd[t + s]; __syncthreads(); }
  const double sumR = sd[0]; __syncthreads();
  sd[t] = aQ; __syncthreads();
  for (int s = 128; s > 0; s >>= 1) { if (t < s) sd[t] += sd[t + s]; __syncthreads(); }
  const double sumQ = sd[0]; __syncthreads();
  if (t == 0) {
    const float rm = (float)(sumR / (double)NB);
    const float ql = (float)sumQ;
    out[0] = rm + ql;
    out[1] = rm;
    out[2] = ql;
    out[3 + NB * NLAYER] = (float)(*dcnt) / (float)NB;
  }
}

// ---------------- host launch ----------------
extern "C" void kernel_launch(void* const* d_in, const int* in_sizes, int n_in,
                              void* d_out, int out_size, void* d_ws, size_t ws_size,
                              hipStream_t stream)
{
  const float* x      = (const float*)d_in[0];
  const float* enc_w1 = (const float*)d_in[1];
  const float* enc_g1 = (const float*)d_in[2];
  const float* enc_b1 = (const float*)d_in[3];
  const float* enc_w2 = (const float*)d_in[4];
  const float* enc_g2 = (const float*)d_in[5];
  const float* enc_b2 = (const float*)d_in[6];
  const float* enc_w3 = (const float*)d_in[7];
  const float* dec_w1 = (const float*)d_in[8];
  const float* dec_g1 = (const float*)d_in[9];
  const float* dec_b1 = (const float*)d_in[10];
  const float* dec_w2 = (const float*)d_in[11];
  const float* dec_g2 = (const float*)d_in[12];
  const float* dec_b2 = (const float*)d_in[13];
  const float* dec_w3 = (const float*)d_in[14];
  const float* codebooks = (const float*)d_in[15];
  float* out = (float*)d_out;

  char* W = (char*)d_ws;
  // region [0,32MB): xh -> h1n0/h1n1 -> h2n0/h2n1 + res0/res1 -> d1n/d2n
  _Float16* xh   = (_Float16*)(W + 0);          // 32MB, dies after enc1
  _Float16* h1n0 = (_Float16*)(W + 0);          // 16MB
  _Float16* h1n1 = (_Float16*)(W + 16777216);   // 16MB
  _Float16* h2n0 = (_Float16*)(W + 0);          // 8MB
  _Float16* h2n1 = (_Float16*)(W + 8388608);    // 8MB
  _Float16* res0 = (_Float16*)(W + 16777216);   // 4MB  (lives through quant loop)
  _Float16* res1 = (_Float16*)(W + 20971520);   // 4MB
  _Float16* d1n  = (_Float16*)(W + 0);          // 8MB (decoder phase)
  _Float16* d2n  = (_Float16*)(W + 25165824);   // 16MB [24,40)
  // region [32,64MB): xl -> h2 f32 / d1 f32 ; res32/esum32 at top
  _Float16* xl    = (_Float16*)(W + 33554432);  // 32MB, dies after enc1
  float*    h2    = (float*)  (W + 33554432);   // 16MB
  float*    d1    = (float*)  (W + 33554432);   // 16MB
  float*    res32 = (float*)  (W + 50331648);   // 8MB
  float*    esum32= (float*)  (W + 58720256);   // 8MB
  // region [64,96MB): h1 f32 -> d2 f32 -> y f16
  float*    h1 = (float*)    (W + 67108864);    // 32MB
  float*    d2 = (float*)    (W + 67108864);    // 32MB
  _Float16* yb = (_Float16*) (W + 67108864);    // 32MB
  // weights region [96MB+)
  _Float16* w1t0 = (_Float16*)(W + 100663296);  // 4MB
  _Float16* w1t1 = (_Float16*)(W + 104857600);  // 4MB
  _Float16* w2t0 = (_Float16*)(W + 109051904);  // 1MB
  _Float16* w2t1 = (_Float16*)(W + 110100480);  // 1MB
  _Float16* w3t0 = (_Float16*)(W + 111149056);  // 256KB
  _Float16* w3t1 = (_Float16*)(W + 111411200);  // 256KB
  _Float16* dw1t = (_Float16*)(W + 111673344);  // 256KB
  _Float16* dw2t = (_Float16*)(W + 111935488);  // 1MB
  _Float16* dw3t = (_Float16*)(W + 112984064);  // 4MB
  _Float16* cbh  = (_Float16*)(W + 117178368);  // 1.5MB
  _Float16* cbl  = (_Float16*)(W + 118751232);  // 1.5MB
  _Float16* esumb= (_Float16*)(W + 120324096);  // 4MB
  float* cn2   = (float*)(W + 124518400);
  float* recon = (float*)(W + 124534784);
  float* qrow  = (float*)(W + 124567552);
  int*   ids   = (int*)  (W + 124600320);
  uint32_t* packed = (uint32_t*)(W + 124698624);
  uint32_t* htab   = (uint32_t*)(W + 124731392); // 64KB
  int*      dcnt   = (int*)     (W + 124796928);
  float*    pval   = (float*)   (W + 124850176); // 512KB [8192][16]
  int*      pidx   = (int*)     (W + 125374464); // 512KB

  // PRNG keys: jax.random.split(jax.random.key(42), 3), partitionable scheme
  uint32_t key0[NLAYER], key1[NLAYER];
  for (int l = 0; l < NLAYER; l++) tf2x32(0u, 42u, 0u, (uint32_t)l, key0[l], key1[l]);

  dim3 blk(256);
  // ---- weight / input / codebook conversion ----
  TJobs J;
  J.w[0] = enc_w1; J.t0[0] = w1t0; J.t1[0] = w1t1; J.K[0] = INDIM; J.N[0] = H1N;
  J.w[1] = enc_w2; J.t0[1] = w2t0; J.t1[1] = w2t1; J.K[1] = H1N;   J.N[1] = H2N;
  J.w[2] = enc_w3; J.t0[2] = w3t0; J.t1[2] = w3t1; J.K[2] = H2N;   J.N[2] = EMB;
  J.w[3] = dec_w1; J.t0[3] = dw1t; J.t1[3] = nullptr; J.K[3] = EMB; J.N[3] = H2N;
  J.w[4] = dec_w2; J.t0[4] = dw2t; J.t1[4] = nullptr; J.K[4] = H2N; J.N[4] = H1N;
  J.w[5] = dec_w3; J.t0[5] = dw3t; J.t1[5] = nullptr; J.K[5] = H1N; J.N[5] = INDIM;
  J.off[0] = 0;
  for (int j = 0; j < 6; j++) J.off[j + 1] = J.off[j] + (J.N[j] / 32) * (J.K[j] / 32);
  tconv_all<<<J.off[6], blk, 0, stream>>>(J);
  cvt2<<<(NB*INDIM)/2048, blk, 0, stream>>>(x, xh, xl, NB*INDIM);
  cbconv<<<NLAYER*KCB, blk, 0, stream>>>(codebooks, cbh, cbl, cn2);
  hash_init<<<HASHN/256, blk, 0, stream>>>(htab, dcnt);

  // ---- encoder (f16 split2, fp32-class) ----
  mgemm<2,0><<<dim3(H1N/128, NB/128), blk, 0, stream>>>(xh, xl, w1t0, w1t1,
      h1, nullptr, nullptr, nullptr, nullptr, nullptr, 0u, 0u, NB, H1N, INDIM);
  silu_ln<H1N,2><<<NB, blk, 0, stream>>>(h1, enc_g1, enc_b1, h1n0, h1n1);
  mgemm<2,0><<<dim3(H2N/128, NB/128), blk, 0, stream>>>(h1n0, h1n1, w2t0, w2t1,
      h2, nullptr, nullptr, nullptr, nullptr, nullptr, 0u, 0u, NB, H2N, H1N);
  silu_ln<H2N,2><<<NB, blk, 0, stream>>>(h2, enc_g2, enc_b2, h2n0, h2n1);
  mgemm<2,2><<<dim3(EMB/128, NB/128), blk, 0, stream>>>(h2n0, h2n1, w3t0, w3t1,
      res32, res0, res1, nullptr, nullptr, nullptr, 0u, 0u, NB, EMB, H2N);

  // ---- quantization (dist GEMM with fused gumbel partial-argmax) ----
  for (int l = 0; l < NLAYER; l++) {
    const float* cbfl = codebooks + (size_t)l * KCB * EMB;
    const size_t co = (size_t)l * KCB * EMB;
    mgemm<2,3><<<dim3(KCB/128, NB/128), blk, 0, stream>>>(res0, res1,
        cbh + co, cbl + co, nullptr, nullptr, nullptr,
        pval, pidx, cn2 + l * KCB, key0[l], key1[l], NB, KCB, EMB);
    sample_update<<<NB, blk, 0, stream>>>(pval, pidx, cbfl,
        res32, esum32, qrow, out + 3, res0, res1, esumb, ids, packed, l);
  }

  // ---- decoder (f16 single product) ----
  mgemm<1,0><<<dim3(H2N/128, NB/128), blk, 0, stream>>>(esumb, nullptr, dw1t, nullptr,
      d1, nullptr, nullptr, nullptr, nullptr, nullptr, 0u, 0u, NB, H2N, EMB);
  silu_ln<H2N,1><<<NB, blk, 0, stream>>>(d1, dec_g1, dec_b1, d1n, nullptr);
  mgemm<1,0><<<dim3(H1N/128, NB/128), blk, 0, stream>>>(d1n, nullptr, dw2t, nullptr,
      d2, nullptr, nullptr, nullptr, nullptr, nullptr, 0u, 0u, NB, H1N, H2N);
  silu_ln<H1N,1><<<NB, blk, 0, stream>>>(d2, dec_g2, dec_b2, d2n, nullptr);
  mgemm<1,1><<<dim3(INDIM/128, NB/128), blk, 0, stream>>>(d2n, nullptr, dw3t, nullptr,
      yb, nullptr, nullptr, nullptr, nullptr, nullptr, 0u, 0u, NB, INDIM, H1N);
  l2norm_recon<<<NB, blk, 0, stream>>>(yb, x, recon);

  // ---- p_unique + scalars ----
  distinct_count<<<NB/256, blk, 0, stream>>>(packed, htab, dcnt);
  finalize<<<1, blk, 0, stream>>>(recon, qrow, dcnt, out);
}